// Round 1
// baseline (114.763 us; speedup 1.0000x reference)
//
#include <hip/hip_runtime.h>
#include <hip/hip_bf16.h>
#include <stdint.h>

// NeighborhoodAttention1D: B=4, L=4096, C=512, H=16, hd=32, K=13
// Pipeline: cvt(x)->bf16 ; W^T->bf16 ; GEMM1(qkv) ; window-attn ; GEMM2(proj)

typedef __attribute__((ext_vector_type(8))) short short8;   // 8 x bf16 (MFMA A/B frag)
typedef __attribute__((ext_vector_type(4))) float f32x4;    // MFMA C/D frag
typedef __attribute__((ext_vector_type(8))) unsigned short u16x8;
typedef __attribute__((ext_vector_type(4))) float float4v;

#define NB 4
#define NL 4096
#define NC 512
#define NH 16
#define HD 32
#define KW 13
#define KHALF 6
#define NM (NB*NL)   // 16384 rows

__device__ __forceinline__ float b2f(unsigned short u) {
  union { unsigned int i; float f; } x; x.i = ((unsigned int)u) << 16; return x.f;
}
__device__ __forceinline__ unsigned short f2b(float f) {
  __hip_bfloat16 h = __float2bfloat16(f);   // RNE
  return __builtin_bit_cast(unsigned short, h);
}
__device__ __forceinline__ void gll16(const unsigned short* g, unsigned short* l) {
  __builtin_amdgcn_global_load_lds(
      (const __attribute__((address_space(1))) void*)g,
      (__attribute__((address_space(3))) void*)l, 16, 0, 0);
}

// ---------------- fp32 -> bf16 convert (x), 8 elems/thread ----------------
__global__ __launch_bounds__(256) void cvt_f32_bf16(const float* __restrict__ in,
                                                    unsigned short* __restrict__ out) {
  long i = (long)blockIdx.x * 256 + threadIdx.x;   // 1,048,576 threads, 8 elems each
  const float4v* in4 = (const float4v*)in;
  float4v a = in4[i * 2];
  float4v b = in4[i * 2 + 1];
  u16x8 u;
  u[0] = f2b(a.x); u[1] = f2b(a.y); u[2] = f2b(a.z); u[3] = f2b(a.w);
  u[4] = f2b(b.x); u[5] = f2b(b.y); u[6] = f2b(b.z); u[7] = f2b(b.w);
  ((u16x8*)out)[i] = u;
}

// ------------- fp32 (R x C) -> bf16 transpose (C x R) ---------------------
__global__ __launch_bounds__(256) void transpose_bf16(const float* __restrict__ in,
                                                      unsigned short* __restrict__ out,
                                                      int R, int C) {
  __shared__ float t[32][33];          // +1 pad: no bank conflicts
  int c0 = blockIdx.x * 32;
  int r0 = blockIdx.y * 32;
  int tx = threadIdx.x;                // 0..31
  int ty = threadIdx.y;                // 0..7
  #pragma unroll
  for (int i = ty; i < 32; i += 8)
    t[i][tx] = in[(long)(r0 + i) * C + c0 + tx];
  __syncthreads();
  #pragma unroll
  for (int i = ty; i < 32; i += 8)
    out[(long)(c0 + i) * R + r0 + tx] = f2b(t[tx][i]);
}

// ---------------- bf16 GEMM:  C[M,N] = A[M,K] * BT[N,K]^T + bias ----------
// 128x128 tile, BK=32, 4 waves (2x2), each wave 64x64 = 4x4 frags of 16x16x32.
template<int OUT_BF16>
__global__ __launch_bounds__(256)
void gemm_bt(const unsigned short* __restrict__ A,
             const unsigned short* __restrict__ BT,
             const float* __restrict__ bias,
             void* __restrict__ Cout,
             int M, int N, int K, int tilesN) {
  __shared__ __align__(16) unsigned short sA[128 * 32];
  __shared__ __align__(16) unsigned short sB[128 * 32];

  int tid  = threadIdx.x;
  int bid  = blockIdx.x;
  int tm   = bid / tilesN, tn = bid % tilesN;
  long mBase = (long)tm * 128;
  long nBase = (long)tn * 128;
  int lane = tid & 63, wave = tid >> 6;
  int wm = wave >> 1, wn = wave & 1;
  int lr = lane & 15, lk = lane >> 4;

  f32x4 acc[4][4];
  #pragma unroll
  for (int i = 0; i < 4; ++i)
    #pragma unroll
    for (int j = 0; j < 4; ++j) acc[i][j] = (f32x4){0.f, 0.f, 0.f, 0.f};

  // staging: 2 x global_load_lds(16B) per operand per K-step per thread
  int rA = tid >> 2;            // 0..63
  int cA = (tid & 3) * 8;       // 0/8/16/24
  const unsigned short* gA0 = A  + (mBase + rA)      * (long)K + cA;
  const unsigned short* gA1 = A  + (mBase + 64 + rA) * (long)K + cA;
  const unsigned short* gB0 = BT + (nBase + rA)      * (long)K + cA;
  const unsigned short* gB1 = BT + (nBase + 64 + rA) * (long)K + cA;
  unsigned short* lA0 = sA + tid * 8;
  unsigned short* lA1 = sA + 2048 + tid * 8;
  unsigned short* lB0 = sB + tid * 8;
  unsigned short* lB1 = sB + 2048 + tid * 8;

  const short8* sA8 = (const short8*)sA;
  const short8* sB8 = (const short8*)sB;

  for (int kt = 0; kt < K; kt += 32) {
    gll16(gA0 + kt, lA0);
    gll16(gA1 + kt, lA1);
    gll16(gB0 + kt, lB0);
    gll16(gB1 + kt, lB1);
    __syncthreads();              // drains vmcnt before barrier (compiler-inserted)

    short8 af[4], bf[4];
    #pragma unroll
    for (int i = 0; i < 4; ++i) af[i] = sA8[(wm * 64 + i * 16 + lr) * 4 + lk];
    #pragma unroll
    for (int j = 0; j < 4; ++j) bf[j] = sB8[(wn * 64 + j * 16 + lr) * 4 + lk];
    #pragma unroll
    for (int i = 0; i < 4; ++i)
      #pragma unroll
      for (int j = 0; j < 4; ++j)
        acc[i][j] = __builtin_amdgcn_mfma_f32_16x16x32_bf16(af[i], bf[j], acc[i][j], 0, 0, 0);
    __syncthreads();
  }

  // epilogue: C/D layout col = lane&15, row = (lane>>4)*4 + r   [m89-verified]
  long rowb = mBase + wm * 64 + (lane >> 4) * 4;
  int  colb = (int)nBase + wn * 64 + lr;
  if (OUT_BF16) {
    unsigned short* C = (unsigned short*)Cout;
    #pragma unroll
    for (int i = 0; i < 4; ++i)
      #pragma unroll
      for (int j = 0; j < 4; ++j) {
        int col = colb + j * 16;
        float bv = bias[col];
        #pragma unroll
        for (int r = 0; r < 4; ++r)
          C[(rowb + i * 16 + r) * (long)N + col] = f2b(acc[i][j][r] + bv);
      }
  } else {
    float* C = (float*)Cout;
    #pragma unroll
    for (int i = 0; i < 4; ++i)
      #pragma unroll
      for (int j = 0; j < 4; ++j) {
        int col = colb + j * 16;
        float bv = bias[col];
        #pragma unroll
        for (int r = 0; r < 4; ++r)
          C[(rowb + i * 16 + r) * (long)N + col] = acc[i][j][r] + bv;
      }
  }
}

// ---------------- neighborhood attention: 1 thread per (b,l,h) ------------
// qkv layout: ((b*L+l)*3 + t)*512 + h*32 + d  (GEMM1 output, bf16)
// out layout: (b*L+l)*512 + h*32 + d          (= GEMM2 A operand, bf16)
__global__ __launch_bounds__(256)
void natt(const unsigned short* __restrict__ qkv, const float* __restrict__ rpb,
          unsigned short* __restrict__ out) {
  int tid = blockIdx.x * 256 + threadIdx.x;     // B*L*H = 262144 threads
  int h = tid & 15;
  int l = (tid >> 4) & (NL - 1);
  int b = tid >> 16;
  const float scale = 0.17677669529663687f;     // 32^-0.5

  long qb = ((long)(b * NL + l) * 3) * NC + h * HD;
  float q[HD];
  {
    const u16x8* q8 = (const u16x8*)(qkv + qb);
    #pragma unroll
    for (int w = 0; w < 4; ++w) {
      u16x8 u = q8[w];
      #pragma unroll
      for (int e = 0; e < 8; ++e) q[w * 8 + e] = b2f(u[e]) * scale;
    }
  }

  int ni = l - KHALF;
  if (ni < 0) ni = 0;
  if (ni > NL - KW) ni = NL - KW;
  const float* rb = rpb + h * (2 * KW - 1) + (ni - l + KW - 1);

  float p[KW];
  float mx = -1e30f;
  #pragma unroll
  for (int j = 0; j < KW; ++j) {
    long kb = ((long)(b * NL + ni + j) * 3 + 1) * NC + h * HD;
    const u16x8* k8 = (const u16x8*)(qkv + kb);
    float s = 0.f;
    #pragma unroll
    for (int w = 0; w < 4; ++w) {
      u16x8 u = k8[w];
      #pragma unroll
      for (int e = 0; e < 8; ++e) s += q[w * 8 + e] * b2f(u[e]);
    }
    s += rb[j];
    p[j] = s;
    mx = fmaxf(mx, s);
  }

  float sum = 0.f;
  #pragma unroll
  for (int j = 0; j < KW; ++j) { p[j] = __expf(p[j] - mx); sum += p[j]; }
  float inv = 1.0f / sum;

  float o[HD];
  #pragma unroll
  for (int d = 0; d < HD; ++d) o[d] = 0.f;
  #pragma unroll
  for (int j = 0; j < KW; ++j) {
    long vb = ((long)(b * NL + ni + j) * 3 + 2) * NC + h * HD;
    const u16x8* v8 = (const u16x8*)(qkv + vb);
    float wj = p[j] * inv;
    #pragma unroll
    for (int w = 0; w < 4; ++w) {
      u16x8 u = v8[w];
      #pragma unroll
      for (int e = 0; e < 8; ++e) o[w * 8 + e] += wj * b2f(u[e]);
    }
  }

  unsigned short* op = out + (long)(b * NL + l) * NC + h * HD;
  #pragma unroll
  for (int w = 0; w < 4; ++w) {
    u16x8 u;
    #pragma unroll
    for (int e = 0; e < 8; ++e) u[e] = f2b(o[w * 8 + e]);
    *((u16x8*)(op + w * 8)) = u;
  }
}

// ---------------------------------------------------------------------------
extern "C" void kernel_launch(void* const* d_in, const int* in_sizes, int n_in,
                              void* d_out, int out_size, void* d_ws, size_t ws_size,
                              hipStream_t stream) {
  const float* x      = (const float*)d_in[0];
  const float* qkv_w  = (const float*)d_in[1];
  const float* qkv_b  = (const float*)d_in[2];
  const float* rpb    = (const float*)d_in[3];
  const float* proj_w = (const float*)d_in[4];
  const float* proj_b = (const float*)d_in[5];
  float* out = (float*)d_out;

  char* ws = (char*)d_ws;
  unsigned short* xb     = (unsigned short*)(ws);              // 16,777,216 B
  unsigned short* qkvwT  = (unsigned short*)(ws + 16777216);   //  1,572,864 B
  unsigned short* projwT = (unsigned short*)(ws + 18350080);   //    524,288 B
  unsigned short* qkvo   = (unsigned short*)(ws + 18874368);   // 50,331,648 B
  unsigned short* attno  = (unsigned short*)(ws + 69206016);   // 16,777,216 B  (total ~86 MB)

  // 1) x -> bf16
  cvt_f32_bf16<<<dim3(4096), dim3(256), 0, stream>>>(x, xb);
  // 2) W^T -> bf16 (so GEMM B-operand is N x K row-major)
  transpose_bf16<<<dim3(48, 16), dim3(32, 8), 0, stream>>>(qkv_w, qkvwT, 512, 1536);
  transpose_bf16<<<dim3(16, 16), dim3(32, 8), 0, stream>>>(proj_w, projwT, 512, 512);
  // 3) qkv = x @ qkv_w + b   (bf16 out)
  gemm_bt<1><<<dim3(128 * 12), dim3(256), 0, stream>>>(xb, qkvwT, qkv_b, qkvo,
                                                       NM, 1536, 512, 12);
  // 4) neighborhood attention
  natt<<<dim3(1024), dim3(256), 0, stream>>>(qkvo, rpb, attno);
  // 5) out = attn @ proj_w + b  (fp32 out)
  gemm_bt<0><<<dim3(128 * 4), dim3(256), 0, stream>>>(attno, projwT, proj_b, out,
                                                      NM, 512, 512, 4);
}

// Round 2
// 109.184 us; speedup vs baseline: 1.0511x; 1.0511x over previous
//
#include <hip/hip_runtime.h>
#include <hip/hip_bf16.h>
#include <stdint.h>

// NeighborhoodAttention1D: B=4, L=4096, C=512, H=16, hd=32, K=13
// cvt(x)->bf16 ; W^T->bf16 ; GEMM1 (256^2 8-phase) ; window-attn ; GEMM2 (256^2 8-phase)

typedef __attribute__((ext_vector_type(8))) short short8;   // 8 x bf16 frag
typedef __attribute__((ext_vector_type(4))) float f32x4;    // MFMA C/D frag
typedef __attribute__((ext_vector_type(8))) unsigned short u16x8;
typedef __attribute__((ext_vector_type(4))) float float4v;

#define NB 4
#define NL 4096
#define NC 512
#define NH 16
#define HD 32
#define KW 13
#define KHALF 6
#define NM (NB*NL)   // 16384 rows

__device__ __forceinline__ float b2f(unsigned short u) {
  union { unsigned int i; float f; } x; x.i = ((unsigned int)u) << 16; return x.f;
}
__device__ __forceinline__ unsigned short f2b(float f) {
  __hip_bfloat16 h = __float2bfloat16(f);   // RNE
  return __builtin_bit_cast(unsigned short, h);
}
__device__ __forceinline__ void gll16(const unsigned short* g, unsigned short* l) {
  __builtin_amdgcn_global_load_lds(
      (const __attribute__((address_space(1))) void*)g,
      (__attribute__((address_space(3))) void*)l, 16, 0, 0);
}

// ---------------- fp32 -> bf16 convert (x), 8 elems/thread ----------------
__global__ __launch_bounds__(256) void cvt_f32_bf16(const float* __restrict__ in,
                                                    unsigned short* __restrict__ out) {
  long i = (long)blockIdx.x * 256 + threadIdx.x;
  const float4v* in4 = (const float4v*)in;
  float4v a = in4[i * 2];
  float4v b = in4[i * 2 + 1];
  u16x8 u;
  u[0] = f2b(a.x); u[1] = f2b(a.y); u[2] = f2b(a.z); u[3] = f2b(a.w);
  u[4] = f2b(b.x); u[5] = f2b(b.y); u[6] = f2b(b.z); u[7] = f2b(b.w);
  ((u16x8*)out)[i] = u;
}

// ------------- fp32 (R x C) -> bf16 transpose (C x R) ---------------------
__global__ __launch_bounds__(256) void transpose_bf16(const float* __restrict__ in,
                                                      unsigned short* __restrict__ out,
                                                      int R, int C) {
  __shared__ float t[32][33];
  int c0 = blockIdx.x * 32;
  int r0 = blockIdx.y * 32;
  int tx = threadIdx.x;
  int ty = threadIdx.y;
  #pragma unroll
  for (int i = ty; i < 32; i += 8)
    t[i][tx] = in[(long)(r0 + i) * C + c0 + tx];
  __syncthreads();
  #pragma unroll
  for (int i = ty; i < 32; i += 8)
    out[(long)(c0 + i) * R + r0 + tx] = f2b(t[tx][i]);
}

// ============ 256x256 8-phase bf16 GEMM (m201-style template) =============
// C[M,N] = A[M,K] * BT[N,K]^T + bias.  K must be 512 (NT=8 K-tiles of 64).
// 512 threads = 8 waves (2M x 4N), per-wave 128x64 output = acc[8][4].
// LDS 128KiB: A[2buf][2half][128][64]bf16, B same at +32768 ushorts.
// Swizzle: byte ^= (row&7)<<4 (linear gll dest + inverse-swz source + swz read).
// Stage stream per iter: p1:kt+1 A0  p2:kt+1 A1  p3:kt+2 B0  p4:kt+2 B1(+vmcnt4)
//                        p5:kt+2 A0  p6:kt+2 A1  p7:kt+3 B0  p8:kt+3 B1(+vmcnt4)
// WAR safe: each region staged >=1 phase after its last ds_read (lgkmcnt(0)
// drained before the intervening barrier). RAW: vmcnt(4) = 2 half-tiles
// outstanding -> everything older landed.

__device__ __forceinline__ void stage_half(const unsigned short* __restrict__ G,
                                           long rowBase, int K, int kt,
                                           unsigned short* ldsDst, int tid) {
  int r  = tid >> 3;                       // 0..63
  int ch = (tid & 7) ^ (r & 7);            // inverse-swizzled source chunk
  const unsigned short* s0 = G + (rowBase + r) * (long)K + kt * 64 + ch * 8;
  gll16(s0, ldsDst + tid * 8);
  gll16(s0 + 64 * (long)K, ldsDst + 4096 + tid * 8);
}

#define BAR() __builtin_amdgcn_s_barrier()
#define LGK0() asm volatile("s_waitcnt lgkmcnt(0)" ::: "memory")
#define VM(N) asm volatile("s_waitcnt vmcnt(" #N ")" ::: "memory")

#define DS_A(BUF, QM) do { \
  const char* _ba = (const char*)(lds + (BUF)*16384 + wm*8192); \
  _Pragma("unroll") for (int ii = 0; ii < 4; ++ii) { \
    int _row = ((QM)*4+ii)*16 + lr; \
    _Pragma("unroll") for (int kb = 0; kb < 2; ++kb) \
      af[ii][kb] = *(const short8*)(_ba + _row*128 + (((kb*4+lk) ^ lr7) * 16)); \
  } \
} while (0)

#define DS_B(BUF, QN, BF) do { \
  const char* _bb = (const char*)(lds + 32768 + (BUF)*16384 + (wn>>1)*8192); \
  _Pragma("unroll") for (int jj = 0; jj < 2; ++jj) { \
    int _row = (wn&1)*64 + ((QN)*2+jj)*16 + lr; \
    _Pragma("unroll") for (int kb = 0; kb < 2; ++kb) \
      BF[jj][kb] = *(const short8*)(_bb + _row*128 + (((kb*4+lk) ^ lr7) * 16)); \
  } \
} while (0)

#define MMA(QM, QN, BF) do { \
  __builtin_amdgcn_s_setprio(1); \
  _Pragma("unroll") for (int ii = 0; ii < 4; ++ii) \
    _Pragma("unroll") for (int jj = 0; jj < 2; ++jj) \
      _Pragma("unroll") for (int kb = 0; kb < 2; ++kb) \
        acc[(QM)*4+ii][(QN)*2+jj] = __builtin_amdgcn_mfma_f32_16x16x32_bf16( \
            af[ii][kb], BF[jj][kb], acc[(QM)*4+ii][(QN)*2+jj], 0, 0, 0); \
  __builtin_amdgcn_s_setprio(0); \
} while (0)

template<int OUT_BF16>
__global__ __launch_bounds__(512, 2)
void gemm256(const unsigned short* __restrict__ A,
             const unsigned short* __restrict__ BT,
             const float* __restrict__ bias,
             void* __restrict__ Cout,
             int M, int N, int K, int tilesN) {
  __shared__ __align__(16) unsigned short lds[65536];   // 128 KiB

  int tid = threadIdx.x;
  int nwg = gridDim.x;                   // divisible by 8 (384 / 128)
  int cpx = nwg >> 3;
  int wg  = ((int)blockIdx.x & 7) * cpx + ((int)blockIdx.x >> 3);  // XCD swizzle
  int tm = wg / tilesN, tn = wg % tilesN;
  long mBase = (long)tm * 256;
  long nBase = (long)tn * 256;

  int lane = tid & 63, wave = tid >> 6;
  int wm = wave >> 2;          // 0..1 : M half
  int wn = wave & 3;           // 0..3 : N quarter
  int lr = lane & 15, lk = lane >> 4, lr7 = lr & 7;

  // LDS dest bases (ushort units)
  unsigned short* A0h0 = lds;
  unsigned short* A0h1 = lds + 8192;
  unsigned short* A1h0 = lds + 16384;
  unsigned short* A1h1 = lds + 16384 + 8192;
  unsigned short* B0h0 = lds + 32768;
  unsigned short* B0h1 = lds + 32768 + 8192;
  unsigned short* B1h0 = lds + 32768 + 16384;
  unsigned short* B1h1 = lds + 32768 + 16384 + 8192;

  f32x4 acc[8][4];
  #pragma unroll
  for (int i = 0; i < 8; ++i)
    #pragma unroll
    for (int j = 0; j < 4; ++j) acc[i][j] = (f32x4){0.f, 0.f, 0.f, 0.f};

  short8 af[4][2], bf0[2][2], bf1[2][2];

  // ---- prologue: kt0 {B0,B1,A0,A1} -> buf0 ; kt1 {B0,B1} -> buf1 ----
  stage_half(BT, nBase,       K, 0, B0h0, tid);
  stage_half(BT, nBase + 128, K, 0, B0h1, tid);
  stage_half(A,  mBase,       K, 0, A0h0, tid);
  stage_half(A,  mBase + 128, K, 0, A0h1, tid);
  stage_half(BT, nBase,       K, 1, B1h0, tid);
  stage_half(BT, nBase + 128, K, 1, B1h1, tid);
  VM(4);                       // kt0 fully landed (kt1 B still in flight)
  BAR();

  #pragma unroll 1
  for (int it = 0; it < 4; ++it) {
    int kt = it * 2;                      // even K-tile -> buf0, odd -> buf1
    bool s2 = (kt + 2) < 8;
    bool s3 = (kt + 3) < 8;

    // p1 -------------------------------------------------- kt, quad (0,0)
    DS_A(0, 0);
    DS_B(0, 0, bf0);
    stage_half(A, mBase, K, kt + 1, A1h0, tid);
    BAR(); LGK0();
    MMA(0, 0, bf0);
    BAR();
    // p2 -------------------------------------------------- kt, quad (0,1)
    DS_B(0, 1, bf1);
    stage_half(A, mBase + 128, K, kt + 1, A1h1, tid);
    BAR(); LGK0();
    MMA(0, 1, bf1);
    BAR();
    // p3 -------------------------------------------------- kt, quad (1,1)
    DS_A(0, 1);
    if (s2) stage_half(BT, nBase, K, kt + 2, B0h0, tid);
    BAR(); LGK0();
    MMA(1, 1, bf1);
    BAR();
    // p4 -------------------------------------------------- kt, quad (1,0)
    if (s2) { stage_half(BT, nBase + 128, K, kt + 2, B0h1, tid); VM(4); }
    else    { VM(0); }
    BAR();
    MMA(1, 0, bf0);
    BAR();
    // p5 ------------------------------------------------ kt+1, quad (0,0)
    DS_A(1, 0);
    DS_B(1, 0, bf0);
    if (s2) stage_half(A, mBase, K, kt + 2, A0h0, tid);
    BAR(); LGK0();
    MMA(0, 0, bf0);
    BAR();
    // p6 ------------------------------------------------ kt+1, quad (0,1)
    DS_B(1, 1, bf1);
    if (s2) stage_half(A, mBase + 128, K, kt + 2, A0h1, tid);
    BAR(); LGK0();
    MMA(0, 1, bf1);
    BAR();
    // p7 ------------------------------------------------ kt+1, quad (1,1)
    DS_A(1, 1);
    if (s3) stage_half(BT, nBase, K, kt + 3, B1h0, tid);
    BAR(); LGK0();
    MMA(1, 1, bf1);
    BAR();
    // p8 ------------------------------------------------ kt+1, quad (1,0)
    if (s3) { stage_half(BT, nBase + 128, K, kt + 3, B1h1, tid); VM(4); }
    BAR();
    MMA(1, 0, bf0);
    BAR();
  }

  // ---- epilogue: C/D layout col = lane&15, row = (lane>>4)*4 + r --------
  long rowb = mBase + wm * 128 + (lane >> 4) * 4;
  int  colb = (int)nBase + wn * 64 + lr;
  if (OUT_BF16) {
    unsigned short* C = (unsigned short*)Cout;
    #pragma unroll
    for (int mi = 0; mi < 8; ++mi)
      #pragma unroll
      for (int nj = 0; nj < 4; ++nj) {
        int col = colb + nj * 16;
        float bv = bias[col];
        #pragma unroll
        for (int r = 0; r < 4; ++r)
          C[(rowb + mi * 16 + r) * (long)N + col] = f2b(acc[mi][nj][r] + bv);
      }
  } else {
    float* C = (float*)Cout;
    #pragma unroll
    for (int mi = 0; mi < 8; ++mi)
      #pragma unroll
      for (int nj = 0; nj < 4; ++nj) {
        int col = colb + nj * 16;
        float bv = bias[col];
        #pragma unroll
        for (int r = 0; r < 4; ++r)
          C[(rowb + mi * 16 + r) * (long)N + col] = acc[mi][nj][r] + bv;
      }
  }
}

// ---------------- neighborhood attention: 1 thread per (b,l,h) ------------
__global__ __launch_bounds__(256)
void natt(const unsigned short* __restrict__ qkv, const float* __restrict__ rpb,
          unsigned short* __restrict__ out) {
  int tid = blockIdx.x * 256 + threadIdx.x;
  int h = tid & 15;
  int l = (tid >> 4) & (NL - 1);
  int b = tid >> 16;
  const float scale = 0.17677669529663687f;

  long qb = ((long)(b * NL + l) * 3) * NC + h * HD;
  float q[HD];
  {
    const u16x8* q8 = (const u16x8*)(qkv + qb);
    #pragma unroll
    for (int w = 0; w < 4; ++w) {
      u16x8 u = q8[w];
      #pragma unroll
      for (int e = 0; e < 8; ++e) q[w * 8 + e] = b2f(u[e]) * scale;
    }
  }

  int ni = l - KHALF;
  if (ni < 0) ni = 0;
  if (ni > NL - KW) ni = NL - KW;
  const float* rb = rpb + h * (2 * KW - 1) + (ni - l + KW - 1);

  float p[KW];
  float mx = -1e30f;
  #pragma unroll
  for (int j = 0; j < KW; ++j) {
    long kb = ((long)(b * NL + ni + j) * 3 + 1) * NC + h * HD;
    const u16x8* k8 = (const u16x8*)(qkv + kb);
    float s = 0.f;
    #pragma unroll
    for (int w = 0; w < 4; ++w) {
      u16x8 u = k8[w];
      #pragma unroll
      for (int e = 0; e < 8; ++e) s += q[w * 8 + e] * b2f(u[e]);
    }
    s += rb[j];
    p[j] = s;
    mx = fmaxf(mx, s);
  }

  float sum = 0.f;
  #pragma unroll
  for (int j = 0; j < KW; ++j) { p[j] = __expf(p[j] - mx); sum += p[j]; }
  float inv = 1.0f / sum;

  float o[HD];
  #pragma unroll
  for (int d = 0; d < HD; ++d) o[d] = 0.f;
  #pragma unroll
  for (int j = 0; j < KW; ++j) {
    long vb = ((long)(b * NL + ni + j) * 3 + 2) * NC + h * HD;
    const u16x8* v8 = (const u16x8*)(qkv + vb);
    float wj = p[j] * inv;
    #pragma unroll
    for (int w = 0; w < 4; ++w) {
      u16x8 u = v8[w];
      #pragma unroll
      for (int e = 0; e < 8; ++e) o[w * 8 + e] += wj * b2f(u[e]);
    }
  }

  unsigned short* op = out + (long)(b * NL + l) * NC + h * HD;
  #pragma unroll
  for (int w = 0; w < 4; ++w) {
    u16x8 u;
    #pragma unroll
    for (int e = 0; e < 8; ++e) u[e] = f2b(o[w * 8 + e]);
    *((u16x8*)(op + w * 8)) = u;
  }
}

// ---------------------------------------------------------------------------
extern "C" void kernel_launch(void* const* d_in, const int* in_sizes, int n_in,
                              void* d_out, int out_size, void* d_ws, size_t ws_size,
                              hipStream_t stream) {
  const float* x      = (const float*)d_in[0];
  const float* qkv_w  = (const float*)d_in[1];
  const float* qkv_b  = (const float*)d_in[2];
  const float* rpb    = (const float*)d_in[3];
  const float* proj_w = (const float*)d_in[4];
  const float* proj_b = (const float*)d_in[5];
  float* out = (float*)d_out;

  char* ws = (char*)d_ws;
  unsigned short* xb     = (unsigned short*)(ws);              // 16,777,216 B
  unsigned short* qkvwT  = (unsigned short*)(ws + 16777216);   //  1,572,864 B
  unsigned short* projwT = (unsigned short*)(ws + 18350080);   //    524,288 B
  unsigned short* qkvo   = (unsigned short*)(ws + 18874368);   // 50,331,648 B
  unsigned short* attno  = (unsigned short*)(ws + 69206016);   // 16,777,216 B

  cvt_f32_bf16<<<dim3(4096), dim3(256), 0, stream>>>(x, xb);
  transpose_bf16<<<dim3(48, 16), dim3(32, 8), 0, stream>>>(qkv_w, qkvwT, 512, 1536);
  transpose_bf16<<<dim3(16, 16), dim3(32, 8), 0, stream>>>(proj_w, projwT, 512, 512);
  // qkv = x @ qkv_w + b   (bf16 out): 64 x 6 = 384 blocks
  gemm256<1><<<dim3(384), dim3(512), 0, stream>>>(xb, qkvwT, qkv_b, qkvo,
                                                  NM, 1536, 512, 6);
  natt<<<dim3(1024), dim3(256), 0, stream>>>(qkvo, rpb, attno);
  // out = attn @ proj_w + b  (fp32 out): 64 x 2 = 128 blocks
  gemm256<0><<<dim3(128), dim3(512), 0, stream>>>(attno, projwT, proj_b, out,
                                                  NM, 512, 512, 2);
}

// Round 3
// 108.757 us; speedup vs baseline: 1.0552x; 1.0039x over previous
//
#include <hip/hip_runtime.h>
#include <hip/hip_bf16.h>
#include <stdint.h>

// NeighborhoodAttention1D: B=4, L=4096, C=512, H=16, hd=32, K=13
// cvt(x)->bf16 ; W^T->bf16 ; GEMM1 (256x128 8-wave dbuf) ; window-attn ; GEMM2

typedef __attribute__((ext_vector_type(8))) short short8;   // 8 x bf16 frag
typedef __attribute__((ext_vector_type(4))) float f32x4;    // MFMA C/D frag
typedef __attribute__((ext_vector_type(8))) unsigned short u16x8;
typedef __attribute__((ext_vector_type(4))) float float4v;

#define NB 4
#define NL 4096
#define NC 512
#define NH 16
#define HD 32
#define KW 13
#define KHALF 6
#define NM (NB*NL)   // 16384 rows

__device__ __forceinline__ float b2f(unsigned short u) {
  union { unsigned int i; float f; } x; x.i = ((unsigned int)u) << 16; return x.f;
}
__device__ __forceinline__ unsigned short f2b(float f) {
  __hip_bfloat16 h = __float2bfloat16(f);   // RNE
  return __builtin_bit_cast(unsigned short, h);
}
__device__ __forceinline__ void gll16(const unsigned short* g, unsigned short* l) {
  __builtin_amdgcn_global_load_lds(
      (const __attribute__((address_space(1))) void*)g,
      (__attribute__((address_space(3))) void*)l, 16, 0, 0);
}

// ---------------- fp32 -> bf16 convert (x), 8 elems/thread ----------------
__global__ __launch_bounds__(256) void cvt_f32_bf16(const float* __restrict__ in,
                                                    unsigned short* __restrict__ out) {
  long i = (long)blockIdx.x * 256 + threadIdx.x;
  const float4v* in4 = (const float4v*)in;
  float4v a = in4[i * 2];
  float4v b = in4[i * 2 + 1];
  u16x8 u;
  u[0] = f2b(a.x); u[1] = f2b(a.y); u[2] = f2b(a.z); u[3] = f2b(a.w);
  u[4] = f2b(b.x); u[5] = f2b(b.y); u[6] = f2b(b.z); u[7] = f2b(b.w);
  ((u16x8*)out)[i] = u;
}

// ------------- fp32 (R x C) -> bf16 transpose (C x R) ---------------------
__global__ __launch_bounds__(256) void transpose_bf16(const float* __restrict__ in,
                                                      unsigned short* __restrict__ out,
                                                      int R, int C) {
  __shared__ float t[32][33];
  int c0 = blockIdx.x * 32;
  int r0 = blockIdx.y * 32;
  int tx = threadIdx.x;
  int ty = threadIdx.y;
  #pragma unroll
  for (int i = ty; i < 32; i += 8)
    t[i][tx] = in[(long)(r0 + i) * C + c0 + tx];
  __syncthreads();
  #pragma unroll
  for (int i = ty; i < 32; i += 8)
    out[(long)(c0 + i) * R + r0 + tx] = f2b(t[tx][i]);
}

// ========= 256x128 8-wave dbuf bf16 GEMM, 4-phase counted-vmcnt ===========
// C[M,N] = A[M,K] * BT[N,K]^T + bias.  K = 512 (8 K-tiles of 64, 4 iters).
// 512 threads = 8 waves (4M x 1..2N): wm=wave>>1 (M quarter), wn=wave&1
// (N half); per-wave output 64x64 = acc[4][4].
// LDS 96KiB: A[2buf][256][64] @0, B[2buf][128][64] @32768 (ushorts).
// Swizzle: chunk ^= (row&7) within 128B rows (both-sides, rule 21).
// Stage stream/iter: P1: A(kt+1)x2  P2: B(kt+2)+VM(2)  P3: A(kt+2)x2
//                    P4: B(kt+3)+VM(2).  VM(2) => oldest 6 of 8 landed =
//                    next K-tile's A+B fully in LDS before its reader phase.

__device__ __forceinline__ void stage_half(const unsigned short* __restrict__ G,
                                           long rowBase, int K, int kt,
                                           unsigned short* ldsDst, int tid) {
  int r  = tid >> 3;                       // 0..63
  int ch = (tid & 7) ^ (r & 7);            // inverse-swizzled source chunk
  const unsigned short* s0 = G + (rowBase + r) * (long)K + kt * 64 + ch * 8;
  gll16(s0, ldsDst + tid * 8);
  gll16(s0 + 64 * (long)K, ldsDst + 4096 + tid * 8);
}

#define BAR() __builtin_amdgcn_s_barrier()
#define LGK0() asm volatile("s_waitcnt lgkmcnt(0)" ::: "memory")
#define VM(N) asm volatile("s_waitcnt vmcnt(" #N ")" ::: "memory")

// af[ii][kb]: A rows wm*64 + (QM*2+ii)*16 + lr, k-chunk kb*4+lk (swizzled)
#define DS_A(BUF, QM) do { \
  const char* _ba = (const char*)(lds + (BUF)*16384); \
  _Pragma("unroll") for (int ii = 0; ii < 2; ++ii) { \
    int _row = wm*64 + ((QM)*2+ii)*16 + lr; \
    _Pragma("unroll") for (int kb = 0; kb < 2; ++kb) \
      af[ii][kb] = *(const short8*)(_ba + _row*128 + (((kb*4+lk) ^ lr7) * 16)); \
  } \
} while (0)

#define DS_B(BUF, QN, BF) do { \
  const char* _bb = (const char*)(lds + 32768 + (BUF)*8192); \
  _Pragma("unroll") for (int jj = 0; jj < 2; ++jj) { \
    int _row = wn*64 + ((QN)*2+jj)*16 + lr; \
    _Pragma("unroll") for (int kb = 0; kb < 2; ++kb) \
      BF[jj][kb] = *(const short8*)(_bb + _row*128 + (((kb*4+lk) ^ lr7) * 16)); \
  } \
} while (0)

#define MMA(QM, QN, BF) do { \
  __builtin_amdgcn_s_setprio(1); \
  _Pragma("unroll") for (int ii = 0; ii < 2; ++ii) \
    _Pragma("unroll") for (int jj = 0; jj < 2; ++jj) \
      _Pragma("unroll") for (int kb = 0; kb < 2; ++kb) \
        acc[(QM)*2+ii][(QN)*2+jj] = __builtin_amdgcn_mfma_f32_16x16x32_bf16( \
            af[ii][kb], BF[jj][kb], acc[(QM)*2+ii][(QN)*2+jj], 0, 0, 0); \
  __builtin_amdgcn_s_setprio(0); \
} while (0)

template<int OUT_BF16>
__global__ __launch_bounds__(512, 2)
void gemm256(const unsigned short* __restrict__ A,
             const unsigned short* __restrict__ BT,
             const float* __restrict__ bias,
             void* __restrict__ Cout,
             int M, int N, int K, int tilesN) {
  __shared__ __align__(16) unsigned short lds[49152];   // 96 KiB

  int tid = threadIdx.x;
  int nwg = gridDim.x;                   // 768 / 256, both %8==0
  int cpx = nwg >> 3;
  int wg  = ((int)blockIdx.x & 7) * cpx + ((int)blockIdx.x >> 3);  // XCD swizzle
  int tm = wg / tilesN, tn = wg % tilesN;
  long mBase = (long)tm * 256;
  long nBase = (long)tn * 128;

  int lane = tid & 63, wave = tid >> 6;
  int wm = wave >> 1;          // 0..3 : M quarter (64 rows)
  int wn = wave & 1;           // 0..1 : N half (64 cols)
  int lr = lane & 15, lk = lane >> 4, lr7 = lr & 7;

  // LDS bases (ushort units)
  unsigned short* A0h0 = lds;                    // buf0 A rows 0-127
  unsigned short* A0h1 = lds + 8192;             // buf0 A rows 128-255
  unsigned short* A1h0 = lds + 16384;
  unsigned short* A1h1 = lds + 16384 + 8192;
  unsigned short* B0   = lds + 32768;            // buf0 B rows 0-127
  unsigned short* B1   = lds + 32768 + 8192;

  f32x4 acc[4][4];
  #pragma unroll
  for (int i = 0; i < 4; ++i)
    #pragma unroll
    for (int j = 0; j < 4; ++j) acc[i][j] = (f32x4){0.f, 0.f, 0.f, 0.f};

  short8 af[2][2], bf0[2][2], bf1[2][2];

  // ---- prologue: kt0 {B,A0,A1} -> buf0 ; kt1 {B} -> buf1 (8 gll16) ----
  stage_half(BT, nBase,       K, 0, B0,   tid);
  stage_half(A,  mBase,       K, 0, A0h0, tid);
  stage_half(A,  mBase + 128, K, 0, A0h1, tid);
  stage_half(BT, nBase,       K, 1, B1,   tid);
  VM(2);                       // kt0 fully landed (kt1 B still in flight)
  BAR();

  #pragma unroll 1
  for (int it = 0; it < 4; ++it) {
    int kt = it * 2;                      // even K-tile -> buf0, odd -> buf1
    bool s2 = (kt + 2) < 8;
    bool s3 = (kt + 3) < 8;

    // P1 ----------------------------------------------- kt: quads (0,0)(0,1)
    DS_A(0, 0);
    DS_B(0, 0, bf0);
    DS_B(0, 1, bf1);
    stage_half(A, mBase,       K, kt + 1, A1h0, tid);
    stage_half(A, mBase + 128, K, kt + 1, A1h1, tid);
    BAR(); LGK0();
    MMA(0, 0, bf0);
    MMA(0, 1, bf1);
    BAR();
    // P2 ----------------------------------------------- kt: quads (1,1)(1,0)
    DS_A(0, 1);
    if (s2) stage_half(BT, nBase, K, kt + 2, B0, tid);
    BAR(); LGK0();
    MMA(1, 1, bf1);
    MMA(1, 0, bf0);
    if (s2) { VM(2); } else { VM(0); }    // kt+1 A,B fully landed
    BAR();
    // P3 --------------------------------------------- kt+1: quads (0,0)(0,1)
    DS_A(1, 0);
    DS_B(1, 0, bf0);
    DS_B(1, 1, bf1);
    if (s2) {
      stage_half(A, mBase,       K, kt + 2, A0h0, tid);
      stage_half(A, mBase + 128, K, kt + 2, A0h1, tid);
    }
    BAR(); LGK0();
    MMA(0, 0, bf0);
    MMA(0, 1, bf1);
    BAR();
    // P4 --------------------------------------------- kt+1: quads (1,1)(1,0)
    DS_A(1, 1);
    if (s3) stage_half(BT, nBase, K, kt + 3, B1, tid);
    BAR(); LGK0();
    MMA(1, 1, bf1);
    MMA(1, 0, bf0);
    if (s2) VM(2);                        // kt+2 A,B landed for next iter
    BAR();
  }

  // ---- epilogue: C/D layout col = lane&15, row = (lane>>4)*4 + r --------
  long rowb = mBase + wm * 64 + (lane >> 4) * 4;
  int  colb = (int)nBase + wn * 64 + lr;
  if (OUT_BF16) {
    unsigned short* C = (unsigned short*)Cout;
    #pragma unroll
    for (int mi = 0; mi < 4; ++mi)
      #pragma unroll
      for (int nj = 0; nj < 4; ++nj) {
        int col = colb + nj * 16;
        float bv = bias[col];
        #pragma unroll
        for (int r = 0; r < 4; ++r)
          C[(rowb + mi * 16 + r) * (long)N + col] = f2b(acc[mi][nj][r] + bv);
      }
  } else {
    float* C = (float*)Cout;
    #pragma unroll
    for (int mi = 0; mi < 4; ++mi)
      #pragma unroll
      for (int nj = 0; nj < 4; ++nj) {
        int col = colb + nj * 16;
        float bv = bias[col];
        #pragma unroll
        for (int r = 0; r < 4; ++r)
          C[(rowb + mi * 16 + r) * (long)N + col] = acc[mi][nj][r] + bv;
      }
  }
}

// ---------------- neighborhood attention: 1 thread per (b,l,h) ------------
__global__ __launch_bounds__(256)
void natt(const unsigned short* __restrict__ qkv, const float* __restrict__ rpb,
          unsigned short* __restrict__ out) {
  int tid = blockIdx.x * 256 + threadIdx.x;
  int h = tid & 15;
  int l = (tid >> 4) & (NL - 1);
  int b = tid >> 16;
  const float scale = 0.17677669529663687f;

  long qb = ((long)(b * NL + l) * 3) * NC + h * HD;
  float q[HD];
  {
    const u16x8* q8 = (const u16x8*)(qkv + qb);
    #pragma unroll
    for (int w = 0; w < 4; ++w) {
      u16x8 u = q8[w];
      #pragma unroll
      for (int e = 0; e < 8; ++e) q[w * 8 + e] = b2f(u[e]) * scale;
    }
  }

  int ni = l - KHALF;
  if (ni < 0) ni = 0;
  if (ni > NL - KW) ni = NL - KW;
  const float* rb = rpb + h * (2 * KW - 1) + (ni - l + KW - 1);

  float p[KW];
  float mx = -1e30f;
  #pragma unroll
  for (int j = 0; j < KW; ++j) {
    long kb = ((long)(b * NL + ni + j) * 3 + 1) * NC + h * HD;
    const u16x8* k8 = (const u16x8*)(qkv + kb);
    float s = 0.f;
    #pragma unroll
    for (int w = 0; w < 4; ++w) {
      u16x8 u = k8[w];
      #pragma unroll
      for (int e = 0; e < 8; ++e) s += q[w * 8 + e] * b2f(u[e]);
    }
    s += rb[j];
    p[j] = s;
    mx = fmaxf(mx, s);
  }

  float sum = 0.f;
  #pragma unroll
  for (int j = 0; j < KW; ++j) { p[j] = __expf(p[j] - mx); sum += p[j]; }
  float inv = 1.0f / sum;

  float o[HD];
  #pragma unroll
  for (int d = 0; d < HD; ++d) o[d] = 0.f;
  #pragma unroll
  for (int j = 0; j < KW; ++j) {
    long vb = ((long)(b * NL + ni + j) * 3 + 2) * NC + h * HD;
    const u16x8* v8 = (const u16x8*)(qkv + vb);
    float wj = p[j] * inv;
    #pragma unroll
    for (int w = 0; w < 4; ++w) {
      u16x8 u = v8[w];
      #pragma unroll
      for (int e = 0; e < 8; ++e) o[w * 8 + e] += wj * b2f(u[e]);
    }
  }

  unsigned short* op = out + (long)(b * NL + l) * NC + h * HD;
  #pragma unroll
  for (int w = 0; w < 4; ++w) {
    u16x8 u;
    #pragma unroll
    for (int e = 0; e < 8; ++e) u[e] = f2b(o[w * 8 + e]);
    *((u16x8*)(op + w * 8)) = u;
  }
}

// ---------------------------------------------------------------------------
extern "C" void kernel_launch(void* const* d_in, const int* in_sizes, int n_in,
                              void* d_out, int out_size, void* d_ws, size_t ws_size,
                              hipStream_t stream) {
  const float* x      = (const float*)d_in[0];
  const float* qkv_w  = (const float*)d_in[1];
  const float* qkv_b  = (const float*)d_in[2];
  const float* rpb    = (const float*)d_in[3];
  const float* proj_w = (const float*)d_in[4];
  const float* proj_b = (const float*)d_in[5];
  float* out = (float*)d_out;

  char* ws = (char*)d_ws;
  unsigned short* xb     = (unsigned short*)(ws);              // 16,777,216 B
  unsigned short* qkvwT  = (unsigned short*)(ws + 16777216);   //  1,572,864 B
  unsigned short* projwT = (unsigned short*)(ws + 18350080);   //    524,288 B
  unsigned short* qkvo   = (unsigned short*)(ws + 18874368);   // 50,331,648 B
  unsigned short* attno  = (unsigned short*)(ws + 69206016);   // 16,777,216 B

  cvt_f32_bf16<<<dim3(4096), dim3(256), 0, stream>>>(x, xb);
  transpose_bf16<<<dim3(48, 16), dim3(32, 8), 0, stream>>>(qkv_w, qkvwT, 512, 1536);
  transpose_bf16<<<dim3(16, 16), dim3(32, 8), 0, stream>>>(proj_w, projwT, 512, 512);
  // qkv = x @ qkv_w + b   (bf16 out): 64 x 12 = 768 blocks = 3.0/CU
  gemm256<1><<<dim3(768), dim3(512), 0, stream>>>(xb, qkvwT, qkv_b, qkvo,
                                                  NM, 1536, 512, 12);
  natt<<<dim3(1024), dim3(256), 0, stream>>>(qkvo, rpb, attno);
  // out = attn @ proj_w + b  (fp32 out): 64 x 4 = 256 blocks = 1.0/CU
  gemm256<0><<<dim3(256), dim3(512), 0, stream>>>(attno, projwT, proj_b, out,
                                                  NM, 512, 512, 4);
}

// Round 4
// 106.880 us; speedup vs baseline: 1.0738x; 1.0176x over previous
//
#include <hip/hip_runtime.h>
#include <hip/hip_bf16.h>
#include <stdint.h>

// NeighborhoodAttention1D: B=4, L=4096, C=512, H=16, hd=32, K=13
// cvt(x)->bf16 ; W^T->bf16 ; GEMM1 (256x128, 3-buf deep pipeline) ; natt ; GEMM2

typedef __attribute__((ext_vector_type(8))) short short8;   // 8 x bf16 frag
typedef __attribute__((ext_vector_type(4))) float f32x4;    // MFMA C/D frag
typedef __attribute__((ext_vector_type(8))) unsigned short u16x8;
typedef __attribute__((ext_vector_type(4))) float float4v;

#define NB 4
#define NL 4096
#define NC 512
#define NH 16
#define HD 32
#define KW 13
#define KHALF 6
#define NM (NB*NL)   // 16384 rows

__device__ __forceinline__ float b2f(unsigned short u) {
  union { unsigned int i; float f; } x; x.i = ((unsigned int)u) << 16; return x.f;
}
__device__ __forceinline__ unsigned short f2b(float f) {
  __hip_bfloat16 h = __float2bfloat16(f);   // RNE
  return __builtin_bit_cast(unsigned short, h);
}
__device__ __forceinline__ void gll16(const unsigned short* g, unsigned short* l) {
  __builtin_amdgcn_global_load_lds(
      (const __attribute__((address_space(1))) void*)g,
      (__attribute__((address_space(3))) void*)l, 16, 0, 0);
}

// ---------------- fp32 -> bf16 convert (x), 8 elems/thread ----------------
__global__ __launch_bounds__(256) void cvt_f32_bf16(const float* __restrict__ in,
                                                    unsigned short* __restrict__ out) {
  long i = (long)blockIdx.x * 256 + threadIdx.x;
  const float4v* in4 = (const float4v*)in;
  float4v a = in4[i * 2];
  float4v b = in4[i * 2 + 1];
  u16x8 u;
  u[0] = f2b(a.x); u[1] = f2b(a.y); u[2] = f2b(a.z); u[3] = f2b(a.w);
  u[4] = f2b(b.x); u[5] = f2b(b.y); u[6] = f2b(b.z); u[7] = f2b(b.w);
  ((u16x8*)out)[i] = u;
}

// ------------- fp32 (R x C) -> bf16 transpose (C x R) ---------------------
__global__ __launch_bounds__(256) void transpose_bf16(const float* __restrict__ in,
                                                      unsigned short* __restrict__ out,
                                                      int R, int C) {
  __shared__ float t[32][33];
  int c0 = blockIdx.x * 32;
  int r0 = blockIdx.y * 32;
  int tx = threadIdx.x;
  int ty = threadIdx.y;
  #pragma unroll
  for (int i = ty; i < 32; i += 8)
    t[i][tx] = in[(long)(r0 + i) * C + c0 + tx];
  __syncthreads();
  #pragma unroll
  for (int i = ty; i < 32; i += 8)
    out[(long)(c0 + i) * R + r0 + tx] = f2b(t[tx][i]);
}

// ===== 256x128 8-wave 3-buffer bf16 GEMM, prefetch distance 2 K-tiles =====
// C[M,N] = A[M,K] * BT[N,K]^T + bias.  K = 512 (8 K-tiles of 64).
// 512 threads = 8 waves: wm=wave>>1 (64-row band), wn=wave&1 (64-col half);
// per-wave output 64x64 = acc[4][4].
// LDS 144KiB: A[3][256][64] @0 (3x16384 ush), B[3][128][64] @49152 (3x8192).
// Swizzle: chunk ^= (row&7) within 128B rows (both-sides, rule 21; R3: 0 conf).
// Pipeline: stage kt+2 during kt (A x4 gll16 in phase A, B x2 in phase B);
// one VM(6) per K-tile at phase-B end = wait tile kt+1 (issued 2 K-tiles /
// ~4 phases earlier -> latency covered), leaving kt+2's 6 loads in flight.
// WAR: buf (kt+2)%3 last read during kt-1, whose end-barrier precedes these
// stage issues. RAW: VM(6)+BAR before kt+1's reader phase.

__device__ __forceinline__ void stage_half(const unsigned short* __restrict__ G,
                                           long rowBase, int K, int kt,
                                           unsigned short* ldsDst, int tid) {
  int r  = tid >> 3;                       // 0..63
  int ch = (tid & 7) ^ (r & 7);            // inverse-swizzled source chunk
  const unsigned short* s0 = G + (rowBase + r) * (long)K + kt * 64 + ch * 8;
  gll16(s0, ldsDst + tid * 8);
  gll16(s0 + 64 * (long)K, ldsDst + 4096 + tid * 8);
}

#define BAR() __builtin_amdgcn_s_barrier()
#define LGK0() asm volatile("s_waitcnt lgkmcnt(0)" ::: "memory")
#define VM(N) asm volatile("s_waitcnt vmcnt(" #N ")" ::: "memory")

// af[ii][kb]: A rows wm*64 + (QM*2+ii)*16 + lr, k-chunk kb*4+lk (swizzled)
#define DS_A(ABASE, QM) do { \
  const char* _ba = (const char*)(ABASE); \
  _Pragma("unroll") for (int ii = 0; ii < 2; ++ii) { \
    int _row = wm*64 + ((QM)*2+ii)*16 + lr; \
    _Pragma("unroll") for (int kb = 0; kb < 2; ++kb) \
      af[ii][kb] = *(const short8*)(_ba + _row*128 + (((kb*4+lk) ^ lr7) * 16)); \
  } \
} while (0)

#define DS_B(BBASE, QN, BF) do { \
  const char* _bb = (const char*)(BBASE); \
  _Pragma("unroll") for (int jj = 0; jj < 2; ++jj) { \
    int _row = wn*64 + ((QN)*2+jj)*16 + lr; \
    _Pragma("unroll") for (int kb = 0; kb < 2; ++kb) \
      BF[jj][kb] = *(const short8*)(_bb + _row*128 + (((kb*4+lk) ^ lr7) * 16)); \
  } \
} while (0)

#define MMA(QM, QN, BF) do { \
  __builtin_amdgcn_s_setprio(1); \
  _Pragma("unroll") for (int ii = 0; ii < 2; ++ii) \
    _Pragma("unroll") for (int jj = 0; jj < 2; ++jj) \
      _Pragma("unroll") for (int kb = 0; kb < 2; ++kb) \
        acc[(QM)*2+ii][(QN)*2+jj] = __builtin_amdgcn_mfma_f32_16x16x32_bf16( \
            af[ii][kb], BF[jj][kb], acc[(QM)*2+ii][(QN)*2+jj], 0, 0, 0); \
  __builtin_amdgcn_s_setprio(0); \
} while (0)

template<int OUT_BF16>
__global__ __launch_bounds__(512, 2)
void gemm256(const unsigned short* __restrict__ A,
             const unsigned short* __restrict__ BT,
             const float* __restrict__ bias,
             void* __restrict__ Cout,
             int M, int N, int K, int tilesN) {
  __shared__ __align__(16) unsigned short lds[73728];   // 144 KiB

  int tid = threadIdx.x;
  int nwg = gridDim.x;                   // 768 / 256, both %8==0
  int cpx = nwg >> 3;
  int wg  = ((int)blockIdx.x & 7) * cpx + ((int)blockIdx.x >> 3);  // XCD swizzle
  int tm = wg / tilesN, tn = wg % tilesN;
  long mBase = (long)tm * 256;
  long nBase = (long)tn * 128;

  int lane = tid & 63, wave = tid >> 6;
  int wm = wave >> 1;          // 0..3 : M quarter (64 rows)
  int wn = wave & 1;           // 0..1 : N half (64 cols)
  int lr = lane & 15, lk = lane >> 4, lr7 = lr & 7;

  f32x4 acc[4][4];
  #pragma unroll
  for (int i = 0; i < 4; ++i)
    #pragma unroll
    for (int j = 0; j < 4; ++j) acc[i][j] = (f32x4){0.f, 0.f, 0.f, 0.f};

  short8 af[2][2], bf0[2][2], bf1[2][2];

  // ---- prologue: stage tiles 0 and 1 (A h0, A h1, B each; 12 gll16) ----
  {
    unsigned short* A0 = lds;                 // buf0
    unsigned short* B0 = lds + 49152;
    unsigned short* A1 = lds + 16384;         // buf1
    unsigned short* B1 = lds + 49152 + 8192;
    stage_half(A,  mBase,       K, 0, A0,        tid);
    stage_half(A,  mBase + 128, K, 0, A0 + 8192, tid);
    stage_half(BT, nBase,       K, 0, B0,        tid);
    stage_half(A,  mBase,       K, 1, A1,        tid);
    stage_half(A,  mBase + 128, K, 1, A1 + 8192, tid);
    stage_half(BT, nBase,       K, 1, B1,        tid);
  }
  VM(6);                       // tile 0 fully landed (tile 1 in flight)
  BAR();

  int bc = 0;                  // buffer of current K-tile
  #pragma unroll 1
  for (int kt = 0; kt < 8; ++kt) {
    int bs = bc == 0 ? 2 : bc - 1;            // (bc+2)%3: buffer for kt+2
    unsigned short* A_cur = lds + bc * 16384;
    unsigned short* B_cur = lds + 49152 + bc * 8192;
    unsigned short* A_stg = lds + bs * 16384;
    unsigned short* B_stg = lds + 49152 + bs * 8192;
    bool st = (kt + 2) < 8;

    // Phase A ------------------------------------- kt: quads (0,0)(0,1)
    DS_A(A_cur, 0);
    DS_B(B_cur, 0, bf0);
    DS_B(B_cur, 1, bf1);
    if (st) {
      stage_half(A, mBase,       K, kt + 2, A_stg,        tid);
      stage_half(A, mBase + 128, K, kt + 2, A_stg + 8192, tid);
    }
    BAR(); LGK0();
    MMA(0, 0, bf0);
    MMA(0, 1, bf1);
    BAR();
    // Phase B ------------------------------------- kt: quads (1,1)(1,0)
    DS_A(A_cur, 1);
    if (st) stage_half(BT, nBase, K, kt + 2, B_stg, tid);
    BAR(); LGK0();
    MMA(1, 1, bf1);
    MMA(1, 0, bf0);
    if (st)              VM(6);   // tile kt+1 landed; kt+2's 6 in flight
    else if (kt + 1 < 8) VM(0);   // last prefetched tile (kt=6 -> tile 7)
    BAR();
    bc = bc == 2 ? 0 : bc + 1;
  }

  // ---- epilogue: C/D layout col = lane&15, row = (lane>>4)*4 + r --------
  long rowb = mBase + wm * 64 + (lane >> 4) * 4;
  int  colb = (int)nBase + wn * 64 + lr;
  if (OUT_BF16) {
    unsigned short* C = (unsigned short*)Cout;
    #pragma unroll
    for (int mi = 0; mi < 4; ++mi)
      #pragma unroll
      for (int nj = 0; nj < 4; ++nj) {
        int col = colb + nj * 16;
        float bv = bias[col];
        #pragma unroll
        for (int r = 0; r < 4; ++r)
          C[(rowb + mi * 16 + r) * (long)N + col] = f2b(acc[mi][nj][r] + bv);
      }
  } else {
    float* C = (float*)Cout;
    #pragma unroll
    for (int mi = 0; mi < 4; ++mi)
      #pragma unroll
      for (int nj = 0; nj < 4; ++nj) {
        int col = colb + nj * 16;
        float bv = bias[col];
        #pragma unroll
        for (int r = 0; r < 4; ++r)
          C[(rowb + mi * 16 + r) * (long)N + col] = acc[mi][nj][r] + bv;
      }
  }
}

// ---------------- neighborhood attention: 1 thread per (b,l,h) ------------
__global__ __launch_bounds__(256)
void natt(const unsigned short* __restrict__ qkv, const float* __restrict__ rpb,
          unsigned short* __restrict__ out) {
  int tid = blockIdx.x * 256 + threadIdx.x;
  int h = tid & 15;
  int l = (tid >> 4) & (NL - 1);
  int b = tid >> 16;
  const float scale = 0.17677669529663687f;

  long qb = ((long)(b * NL + l) * 3) * NC + h * HD;
  float q[HD];
  {
    const u16x8* q8 = (const u16x8*)(qkv + qb);
    #pragma unroll
    for (int w = 0; w < 4; ++w) {
      u16x8 u = q8[w];
      #pragma unroll
      for (int e = 0; e < 8; ++e) q[w * 8 + e] = b2f(u[e]) * scale;
    }
  }

  int ni = l - KHALF;
  if (ni < 0) ni = 0;
  if (ni > NL - KW) ni = NL - KW;
  const float* rb = rpb + h * (2 * KW - 1) + (ni - l + KW - 1);

  float p[KW];
  float mx = -1e30f;
  #pragma unroll
  for (int j = 0; j < KW; ++j) {
    long kb = ((long)(b * NL + ni + j) * 3 + 1) * NC + h * HD;
    const u16x8* k8 = (const u16x8*)(qkv + kb);
    float s = 0.f;
    #pragma unroll
    for (int w = 0; w < 4; ++w) {
      u16x8 u = k8[w];
      #pragma unroll
      for (int e = 0; e < 8; ++e) s += q[w * 8 + e] * b2f(u[e]);
    }
    s += rb[j];
    p[j] = s;
    mx = fmaxf(mx, s);
  }

  float sum = 0.f;
  #pragma unroll
  for (int j = 0; j < KW; ++j) { p[j] = __expf(p[j] - mx); sum += p[j]; }
  float inv = 1.0f / sum;

  float o[HD];
  #pragma unroll
  for (int d = 0; d < HD; ++d) o[d] = 0.f;
  #pragma unroll
  for (int j = 0; j < KW; ++j) {
    long vb = ((long)(b * NL + ni + j) * 3 + 2) * NC + h * HD;
    const u16x8* v8 = (const u16x8*)(qkv + vb);
    float wj = p[j] * inv;
    #pragma unroll
    for (int w = 0; w < 4; ++w) {
      u16x8 u = v8[w];
      #pragma unroll
      for (int e = 0; e < 8; ++e) o[w * 8 + e] += wj * b2f(u[e]);
    }
  }

  unsigned short* op = out + (long)(b * NL + l) * NC + h * HD;
  #pragma unroll
  for (int w = 0; w < 4; ++w) {
    u16x8 u;
    #pragma unroll
    for (int e = 0; e < 8; ++e) u[e] = f2b(o[w * 8 + e]);
    *((u16x8*)(op + w * 8)) = u;
  }
}

// ---------------------------------------------------------------------------
extern "C" void kernel_launch(void* const* d_in, const int* in_sizes, int n_in,
                              void* d_out, int out_size, void* d_ws, size_t ws_size,
                              hipStream_t stream) {
  const float* x      = (const float*)d_in[0];
  const float* qkv_w  = (const float*)d_in[1];
  const float* qkv_b  = (const float*)d_in[2];
  const float* rpb    = (const float*)d_in[3];
  const float* proj_w = (const float*)d_in[4];
  const float* proj_b = (const float*)d_in[5];
  float* out = (float*)d_out;

  char* ws = (char*)d_ws;
  unsigned short* xb     = (unsigned short*)(ws);              // 16,777,216 B
  unsigned short* qkvwT  = (unsigned short*)(ws + 16777216);   //  1,572,864 B
  unsigned short* projwT = (unsigned short*)(ws + 18350080);   //    524,288 B
  unsigned short* qkvo   = (unsigned short*)(ws + 18874368);   // 50,331,648 B
  unsigned short* attno  = (unsigned short*)(ws + 69206016);   // 16,777,216 B

  cvt_f32_bf16<<<dim3(4096), dim3(256), 0, stream>>>(x, xb);
  transpose_bf16<<<dim3(48, 16), dim3(32, 8), 0, stream>>>(qkv_w, qkvwT, 512, 1536);
  transpose_bf16<<<dim3(16, 16), dim3(32, 8), 0, stream>>>(proj_w, projwT, 512, 512);
  // qkv = x @ qkv_w + b   (bf16 out): 64 x 12 = 768 blocks = 3.0/CU
  gemm256<1><<<dim3(768), dim3(512), 0, stream>>>(xb, qkvwT, qkv_b, qkvo,
                                                  NM, 1536, 512, 12);
  natt<<<dim3(1024), dim3(256), 0, stream>>>(qkvo, rpb, attno);
  // out = attn @ proj_w + b  (fp32 out): 64 x 4 = 256 blocks = 1.0/CU
  gemm256<0><<<dim3(256), dim3(512), 0, stream>>>(attno, projwT, proj_b, out,
                                                  NM, 512, 512, 4);
}

// Round 6
// 106.521 us; speedup vs baseline: 1.0774x; 1.0034x over previous
//
#include <hip/hip_runtime.h>
#include <hip/hip_bf16.h>
#include <stdint.h>

// NeighborhoodAttention1D: B=4, L=4096, C=512, H=16, hd=32, K=13
// cvt(x)->bf16 ; W^T->bf16 ; GEMM1+GEMM2 = m201-style 256^2 8-phase ; natt

typedef __attribute__((ext_vector_type(8))) short short8;   // 8 x bf16 frag
typedef __attribute__((ext_vector_type(4))) float f32x4;    // MFMA C/D frag
typedef __attribute__((ext_vector_type(8))) unsigned short u16x8;
typedef __attribute__((ext_vector_type(4))) float float4v;

#define NB 4
#define NL 4096
#define NC 512
#define NH 16
#define HD 32
#define KW 13
#define KHALF 6
#define NM (NB*NL)   // 16384 rows

__device__ __forceinline__ float b2f(unsigned short u) {
  union { unsigned int i; float f; } x; x.i = ((unsigned int)u) << 16; return x.f;
}
__device__ __forceinline__ unsigned short f2b(float f) {
  __hip_bfloat16 h = __float2bfloat16(f);   // RNE
  return __builtin_bit_cast(unsigned short, h);
}
__device__ __forceinline__ void gll16(const unsigned short* g, unsigned short* l) {
  __builtin_amdgcn_global_load_lds(
      (const __attribute__((address_space(1))) void*)g,
      (__attribute__((address_space(3))) void*)l, 16, 0, 0);
}

// ---------------- fp32 -> bf16 convert (x), 8 elems/thread ----------------
__global__ __launch_bounds__(256) void cvt_f32_bf16(const float* __restrict__ in,
                                                    unsigned short* __restrict__ out) {
  long i = (long)blockIdx.x * 256 + threadIdx.x;
  const float4v* in4 = (const float4v*)in;
  float4v a = in4[i * 2];
  float4v b = in4[i * 2 + 1];
  u16x8 u;
  u[0] = f2b(a.x); u[1] = f2b(a.y); u[2] = f2b(a.z); u[3] = f2b(a.w);
  u[4] = f2b(b.x); u[5] = f2b(b.y); u[6] = f2b(b.z); u[7] = f2b(b.w);
  ((u16x8*)out)[i] = u;
}

// ------------- fp32 (R x C) -> bf16 transpose (C x R) ---------------------
__global__ __launch_bounds__(256) void transpose_bf16(const float* __restrict__ in,
                                                      unsigned short* __restrict__ out,
                                                      int R, int C) {
  __shared__ float t[32][33];
  int c0 = blockIdx.x * 32;
  int r0 = blockIdx.y * 32;
  int tx = threadIdx.x;
  int ty = threadIdx.y;
  #pragma unroll
  for (int i = ty; i < 32; i += 8)
    t[i][tx] = in[(long)(r0 + i) * C + c0 + tx];
  __syncthreads();
  #pragma unroll
  for (int i = ty; i < 32; i += 8)
    out[(long)(c0 + i) * R + r0 + tx] = f2b(t[tx][i]);
}

// ========== 256x256 8-phase bf16 GEMM (m201 template, K=512) ==============
// C[M,N] = A[M,K]*BT[N,K]^T + bias. 8 waves 2M x 4N, per-wave 128x64 out
// (acc[8][4], AI = 42.7 FLOP/LDS-byte > 40 breakeven).
// LDS 128KiB: A[2buf][256][64] @0, B[2buf][256][64] @32768 ush.
// K=512 -> 8 K-tiles of 64, 4 iterations x 8 phases. Per phase:
//   {ds_read quadrant | stage 1 half-tile | BAR | lgkmcnt(0)+schedbar |
//    setprio(1) 16 MFMA setprio(0) | [VM @p4/p8] | BAR}
// Stage schedule iter i: p1:T(2i+1).A0 p2:T(2i+1).A1 p3:T(2i+2).B0
//   p4:T(2i+2).B1 p5:T(2i+2).A0 p6:T(2i+2).A1 p7:T(2i+3).B0 p8:T(2i+3).B1
// (guards: p3..p6 while 2i+2<8 i.e. i<3; p7/p8 while 2i+3<8 i.e. i<3 --
//  R5 BUG was i<2 here: T7.B never staged, K-tile 7 used stale T5.B.)
// RAW ledger: P4 VM(4): outstanding {T(2i+1).B4, T(2i+1).A4, T(2i+2).B4}
//   -> leaves T(2i+2).B, T(2i+1) complete before P5. P8 VM(4): outstanding
//   {T(2i+2).B4, T(2i+2).A4, T(2i+3).B4} -> leaves T(2i+3).B, T(2i+2)
//   complete before next P1. Tail i=3: P4 VM(0) drains T7.A+T7.B.
// WAR: every stage phase strictly follows the last reader phase of that
//   LDS region (reads drain at that phase's lgkmcnt(0) before its end-BAR).
// Swizzle: chunk ^= (row&7), both-sides (R2-verified: 0 bank conflicts).

__device__ __forceinline__ void stage_half(const unsigned short* __restrict__ G,
                                           long rowBase, int K, int kt,
                                           unsigned short* ldsDst, int tid) {
  int r  = tid >> 3;                       // 0..63
  int ch = (tid & 7) ^ (r & 7);            // inverse-swizzled source chunk
  const unsigned short* s0 = G + (rowBase + r) * (long)K + kt * 64 + ch * 8;
  gll16(s0, ldsDst + tid * 8);
  gll16(s0 + 64 * (long)K, ldsDst + 4096 + tid * 8);
}

#define BAR() __builtin_amdgcn_s_barrier()
#define LGK0() do { asm volatile("s_waitcnt lgkmcnt(0)" ::: "memory"); \
                    __builtin_amdgcn_sched_barrier(0); } while (0)
#define VM(N) asm volatile("s_waitcnt vmcnt(" #N ")" ::: "memory")

// aQ[ii][kb] <- A rows wm*128 + ((HI)*4+ii)*16 + lr, k-chunk (kb*4+lk)^lr7
#define LDA(ABASE, HI) do { \
  const char* _ba = (const char*)(ABASE); \
  _Pragma("unroll") for (int ii = 0; ii < 4; ++ii) { \
    int _row = wm*128 + ((HI)*4+ii)*16 + lr; \
    _Pragma("unroll") for (int kb = 0; kb < 2; ++kb) \
      aQ[ii][kb] = *(const short8*)(_ba + _row*128 + (((kb*4+lk) ^ lr7) * 16)); \
  } \
} while (0)

// bF[NJ][kb] <- B row wn*64 + (NJ)*16 + lr
#define LDB(BBASE, NJ) do { \
  const char* _bb = (const char*)(BBASE); \
  int _row = wn*64 + (NJ)*16 + lr; \
  _Pragma("unroll") for (int kb = 0; kb < 2; ++kb) \
    bF[NJ][kb] = *(const short8*)(_bb + _row*128 + (((kb*4+lk) ^ lr7) * 16)); \
} while (0)

#define MMAQ(MIH, NJH) do { \
  __builtin_amdgcn_s_setprio(1); \
  _Pragma("unroll") for (int ii = 0; ii < 4; ++ii) \
    _Pragma("unroll") for (int jj = 0; jj < 2; ++jj) \
      _Pragma("unroll") for (int kb = 0; kb < 2; ++kb) \
        acc[(MIH)+ii][(NJH)+jj] = __builtin_amdgcn_mfma_f32_16x16x32_bf16( \
            aQ[ii][kb], bF[(NJH)+jj][kb], acc[(MIH)+ii][(NJH)+jj], 0, 0, 0); \
  __builtin_amdgcn_s_setprio(0); \
} while (0)

template<int OUT_BF16>
__global__ __launch_bounds__(512, 2)
void gemm256(const unsigned short* __restrict__ Ag,
             const unsigned short* __restrict__ Bg,
             const float* __restrict__ bias,
             void* __restrict__ Cout,
             int M, int N, int K, int tilesN) {
  __shared__ __align__(16) unsigned short lds[65536];   // 128 KiB

  int tid = threadIdx.x;
  int nwg = gridDim.x;                   // 384 / 128, both %8==0
  int cpx = nwg >> 3;
  int wg  = ((int)blockIdx.x & 7) * cpx + ((int)blockIdx.x >> 3);  // XCD swizzle
  int tm = wg / tilesN, tn = wg % tilesN;
  long mBase = (long)tm * 256;
  long nBase = (long)tn * 256;

  int lane = tid & 63, wave = tid >> 6;
  int wm = wave >> 2;          // 0..1 : M half (128 rows)
  int wn = wave & 3;           // 0..3 : N quarter (64 cols)
  int lr = lane & 15, lk = lane >> 4, lr7 = lr & 7;

  unsigned short* A0 = lds;              // buf0 A (256x64)
  unsigned short* A1 = lds + 16384;      // buf1 A
  unsigned short* B0 = lds + 32768;      // buf0 B (256x64)
  unsigned short* B1 = lds + 49152;      // buf1 B

  f32x4 acc[8][4];
  #pragma unroll
  for (int i = 0; i < 8; ++i)
    #pragma unroll
    for (int j = 0; j < 4; ++j) acc[i][j] = (f32x4){0.f, 0.f, 0.f, 0.f};

  short8 aQ[4][2], bF[4][2];

  // ---- prologue: T0 {A0,A1,B0,B1}, T1 {B0,B1}  (6 half-tiles) ----
  stage_half(Ag, mBase,       K, 0, A0,        tid);
  stage_half(Ag, mBase + 128, K, 0, A0 + 8192, tid);
  stage_half(Bg, nBase,       K, 0, B0,        tid);
  stage_half(Bg, nBase + 128, K, 0, B0 + 8192, tid);
  stage_half(Bg, nBase,       K, 1, B1,        tid);
  stage_half(Bg, nBase + 128, K, 1, B1 + 8192, tid);
  VM(4);                       // T0 fully landed (T1.B in flight)
  BAR();

  #pragma unroll
  for (int i = 0; i < 4; ++i) {
    // ---- K-tile 2i (buf0) ----
    // P1: Q(mi0-3, nj0-1)
    LDA(A0, 0);
    LDB(B0, 0); LDB(B0, 1);
    stage_half(Ag, mBase, K, 2*i + 1, A1, tid);
    BAR(); LGK0();
    MMAQ(0, 0);
    BAR();
    // P2: Q(mi0-3, nj2-3)
    LDB(B0, 2); LDB(B0, 3);
    stage_half(Ag, mBase + 128, K, 2*i + 1, A1 + 8192, tid);
    BAR(); LGK0();
    MMAQ(0, 2);
    BAR();
    // P3: Q(mi4-7, nj2-3)
    LDA(A0, 1);
    if (i < 3) stage_half(Bg, nBase, K, 2*i + 2, B0, tid);
    BAR(); LGK0();
    MMAQ(4, 2);
    BAR();
    // P4: Q(mi4-7, nj0-1)   [no reads]
    if (i < 3) stage_half(Bg, nBase + 128, K, 2*i + 2, B0 + 8192, tid);
    BAR();
    MMAQ(4, 0);
    if (i < 3) { VM(4); } else { VM(0); }   // T(2i+1) complete
    BAR();
    // ---- K-tile 2i+1 (buf1) ----
    // P5: Q(mi0-3, nj0-1)
    LDA(A1, 0);
    LDB(B1, 0); LDB(B1, 1);
    if (i < 3) stage_half(Ag, mBase, K, 2*i + 2, A0, tid);
    BAR(); LGK0();
    MMAQ(0, 0);
    BAR();
    // P6: Q(mi0-3, nj2-3)
    LDB(B1, 2); LDB(B1, 3);
    if (i < 3) stage_half(Ag, mBase + 128, K, 2*i + 2, A0 + 8192, tid);
    BAR(); LGK0();
    MMAQ(0, 2);
    BAR();
    // P7: Q(mi4-7, nj2-3)
    LDA(A1, 1);
    if (i < 3) stage_half(Bg, nBase, K, 2*i + 3, B1, tid);   // FIX: was i<2
    BAR(); LGK0();
    MMAQ(4, 2);
    BAR();
    // P8: Q(mi4-7, nj0-1)   [no reads]
    if (i < 3) stage_half(Bg, nBase + 128, K, 2*i + 3, B1 + 8192, tid);  // FIX
    BAR();
    MMAQ(4, 0);
    if (i < 3) VM(4);                       // T(2i+2) complete
    BAR();
  }

  // ---- epilogue: C/D layout col = lane&15, row = (lane>>4)*4 + r --------
  long rowb = mBase + wm * 128 + (lane >> 4) * 4;
  int  colb = (int)nBase + wn * 64 + lr;
  if (OUT_BF16) {
    unsigned short* C = (unsigned short*)Cout;
    #pragma unroll
    for (int mi = 0; mi < 8; ++mi)
      #pragma unroll
      for (int nj = 0; nj < 4; ++nj) {
        int col = colb + nj * 16;
        float bv = bias[col];
        #pragma unroll
        for (int r = 0; r < 4; ++r)
          C[(rowb + mi * 16 + r) * (long)N + col] = f2b(acc[mi][nj][r] + bv);
      }
  } else {
    float* C = (float*)Cout;
    #pragma unroll
    for (int mi = 0; mi < 8; ++mi)
      #pragma unroll
      for (int nj = 0; nj < 4; ++nj) {
        int col = colb + nj * 16;
        float bv = bias[col];
        #pragma unroll
        for (int r = 0; r < 4; ++r)
          C[(rowb + mi * 16 + r) * (long)N + col] = acc[mi][nj][r] + bv;
      }
  }
}

// ---------------- neighborhood attention: 1 thread per (b,l,h) ------------
__global__ __launch_bounds__(256)
void natt(const unsigned short* __restrict__ qkv, const float* __restrict__ rpb,
          unsigned short* __restrict__ out) {
  int tid = blockIdx.x * 256 + threadIdx.x;
  int h = tid & 15;
  int l = (tid >> 4) & (NL - 1);
  int b = tid >> 16;
  const float scale = 0.17677669529663687f;

  long qb = ((long)(b * NL + l) * 3) * NC + h * HD;
  float q[HD];
  {
    const u16x8* q8 = (const u16x8*)(qkv + qb);
    #pragma unroll
    for (int w = 0; w < 4; ++w) {
      u16x8 u = q8[w];
      #pragma unroll
      for (int e = 0; e < 8; ++e) q[w * 8 + e] = b2f(u[e]) * scale;
    }
  }

  int ni = l - KHALF;
  if (ni < 0) ni = 0;
  if (ni > NL - KW) ni = NL - KW;
  const float* rb = rpb + h * (2 * KW - 1) + (ni - l + KW - 1);

  float p[KW];
  float mx = -1e30f;
  #pragma unroll
  for (int j = 0; j < KW; ++j) {
    long kb = ((long)(b * NL + ni + j) * 3 + 1) * NC + h * HD;
    const u16x8* k8 = (const u16x8*)(qkv + kb);
    float s = 0.f;
    #pragma unroll
    for (int w = 0; w < 4; ++w) {
      u16x8 u = k8[w];
      #pragma unroll
      for (int e = 0; e < 8; ++e) s += q[w * 8 + e] * b2f(u[e]);
    }
    s += rb[j];
    p[j] = s;
    mx = fmaxf(mx, s);
  }

  float sum = 0.f;
  #pragma unroll
  for (int j = 0; j < KW; ++j) { p[j] = __expf(p[j] - mx); sum += p[j]; }
  float inv = 1.0f / sum;

  float o[HD];
  #pragma unroll
  for (int d = 0; d < HD; ++d) o[d] = 0.f;
  #pragma unroll
  for (int j = 0; j < KW; ++j) {
    long vb = ((long)(b * NL + ni + j) * 3 + 2) * NC + h * HD;
    const u16x8* v8 = (const u16x8*)(qkv + vb);
    float wj = p[j] * inv;
    #pragma unroll
    for (int w = 0; w < 4; ++w) {
      u16x8 u = v8[w];
      #pragma unroll
      for (int e = 0; e < 8; ++e) o[w * 8 + e] += wj * b2f(u[e]);
    }
  }

  unsigned short* op = out + (long)(b * NL + l) * NC + h * HD;
  #pragma unroll
  for (int w = 0; w < 4; ++w) {
    u16x8 u;
    #pragma unroll
    for (int e = 0; e < 8; ++e) u[e] = f2b(o[w * 8 + e]);
    *((u16x8*)(op + w * 8)) = u;
  }
}

// ---------------------------------------------------------------------------
extern "C" void kernel_launch(void* const* d_in, const int* in_sizes, int n_in,
                              void* d_out, int out_size, void* d_ws, size_t ws_size,
                              hipStream_t stream) {
  const float* x      = (const float*)d_in[0];
  const float* qkv_w  = (const float*)d_in[1];
  const float* qkv_b  = (const float*)d_in[2];
  const float* rpb    = (const float*)d_in[3];
  const float* proj_w = (const float*)d_in[4];
  const float* proj_b = (const float*)d_in[5];
  float* out = (float*)d_out;

  char* ws = (char*)d_ws;
  unsigned short* xb     = (unsigned short*)(ws);              // 16,777,216 B
  unsigned short* qkvwT  = (unsigned short*)(ws + 16777216);   //  1,572,864 B
  unsigned short* projwT = (unsigned short*)(ws + 18350080);   //    524,288 B
  unsigned short* qkvo   = (unsigned short*)(ws + 18874368);   // 50,331,648 B
  unsigned short* attno  = (unsigned short*)(ws + 69206016);   // 16,777,216 B

  cvt_f32_bf16<<<dim3(4096), dim3(256), 0, stream>>>(x, xb);
  transpose_bf16<<<dim3(48, 16), dim3(32, 8), 0, stream>>>(qkv_w, qkvwT, 512, 1536);
  transpose_bf16<<<dim3(16, 16), dim3(32, 8), 0, stream>>>(proj_w, projwT, 512, 512);
  // qkv = x @ qkv_w + b   (bf16 out): 64 x 6 = 384 blocks
  gemm256<1><<<dim3(384), dim3(512), 0, stream>>>(xb, qkvwT, qkv_b, qkvo,
                                                  NM, 1536, 512, 6);
  natt<<<dim3(1024), dim3(256), 0, stream>>>(qkvo, rpb, attno);
  // out = attn @ proj_w + b  (fp32 out): 64 x 2 = 128 blocks
  gemm256<0><<<dim3(128), dim3(512), 0, stream>>>(attno, projwT, proj_b, out,
                                                  NM, 512, 512, 2);
}

// Round 7
// 101.598 us; speedup vs baseline: 1.1296x; 1.0485x over previous
//
#include <hip/hip_runtime.h>
#include <hip/hip_bf16.h>
#include <stdint.h>

// NeighborhoodAttention1D: B=4, L=4096, C=512, H=16, hd=32, K=13
// cvt(x)->bf16 ; W^T->bf16 ; GEMM1+GEMM2 = 128^2 dbuf 2-blocks/CU ; natt

typedef __attribute__((ext_vector_type(8))) short short8;   // 8 x bf16 frag
typedef __attribute__((ext_vector_type(4))) float f32x4;    // MFMA C/D frag
typedef __attribute__((ext_vector_type(8))) unsigned short u16x8;
typedef __attribute__((ext_vector_type(4))) float float4v;

#define NB 4
#define NL 4096
#define NC 512
#define NH 16
#define HD 32
#define KW 13
#define KHALF 6
#define NM (NB*NL)   // 16384 rows

__device__ __forceinline__ float b2f(unsigned short u) {
  union { unsigned int i; float f; } x; x.i = ((unsigned int)u) << 16; return x.f;
}
__device__ __forceinline__ unsigned short f2b(float f) {
  __hip_bfloat16 h = __float2bfloat16(f);   // RNE
  return __builtin_bit_cast(unsigned short, h);
}
__device__ __forceinline__ void gll16(const unsigned short* g, unsigned short* l) {
  __builtin_amdgcn_global_load_lds(
      (const __attribute__((address_space(1))) void*)g,
      (__attribute__((address_space(3))) void*)l, 16, 0, 0);
}

// ---------------- fp32 -> bf16 convert (x), 8 elems/thread ----------------
__global__ __launch_bounds__(256) void cvt_f32_bf16(const float* __restrict__ in,
                                                    unsigned short* __restrict__ out) {
  long i = (long)blockIdx.x * 256 + threadIdx.x;
  const float4v* in4 = (const float4v*)in;
  float4v a = in4[i * 2];
  float4v b = in4[i * 2 + 1];
  u16x8 u;
  u[0] = f2b(a.x); u[1] = f2b(a.y); u[2] = f2b(a.z); u[3] = f2b(a.w);
  u[4] = f2b(b.x); u[5] = f2b(b.y); u[6] = f2b(b.z); u[7] = f2b(b.w);
  ((u16x8*)out)[i] = u;
}

// ------------- fp32 (R x C) -> bf16 transpose (C x R) ---------------------
__global__ __launch_bounds__(256) void transpose_bf16(const float* __restrict__ in,
                                                      unsigned short* __restrict__ out,
                                                      int R, int C) {
  __shared__ float t[32][33];
  int c0 = blockIdx.x * 32;
  int r0 = blockIdx.y * 32;
  int tx = threadIdx.x;
  int ty = threadIdx.y;
  #pragma unroll
  for (int i = ty; i < 32; i += 8)
    t[i][tx] = in[(long)(r0 + i) * C + c0 + tx];
  __syncthreads();
  #pragma unroll
  for (int i = ty; i < 32; i += 8)
    out[(long)(c0 + i) * R + r0 + tx] = f2b(t[tx][i]);
}

// ====== 128x128 bf16 GEMM, BK=64 dbuf, 64KB LDS -> 2 blocks/CU ============
// C[M,N] = A[M,K]*BT[N,K]^T + bias. K=512 -> 8 K-tiles of 64.
// 256 threads = 4 waves (2M x 2N), per-wave 64x64 out = acc[4][4].
// LDS 64KB: A[2][128][64] @0/@8192, B[2][128][64] @16384/@24576 (ush).
// Rationale (R6 post-mortem): 1-block/CU structures idle on every
// barrier/wait (occupancy 13%); 2 blocks/CU restores cross-block overlap.
// Per K-tile kt (buf b=kt&1):
//   1. ds_read 16 b128 (A 8, B 8) from buf b ; lgkmcnt(0)
//   2. BAR                      // all waves' reads of buf b complete
//   3. stage T(kt+2) -> buf b   // WAR safe by step-2 BAR (8 gll16/thread)
//   4. 32 MFMA
//   5. VM(8)                    // retires T(kt+1) (kt+2's 8 remain)
//   6. BAR                      // next iter may read buf b^1
// vmcnt ledger: outstanding before VM = {T(kt+1):8, T(kt+2):8} -> VM(8)
// guarantees T(kt+1) landed. kt=6: T8 not staged -> VM(0) drains T7.
// Swizzle: chunk ^= (row&7), both-sides (R2/R6-verified: 0 conflicts).

__device__ __forceinline__ void stage_tile(const unsigned short* __restrict__ G,
                                           long rowBase, int K, int kt,
                                           unsigned short* ldsDst, int tid) {
  int r  = tid >> 3;                       // 0..31
  int ch = (tid & 7) ^ (r & 7);            // inverse-swizzled source chunk
  const unsigned short* s0 = G + (rowBase + r) * (long)K + kt * 64 + ch * 8;
  unsigned short* d0 = ldsDst + tid * 8;
  #pragma unroll
  for (int q = 0; q < 4; ++q)              // rows r, r+32, r+64, r+96
    gll16(s0 + (long)32 * q * K, d0 + 2048 * q);
}

#define BAR() __builtin_amdgcn_s_barrier()
#define LGK0() do { asm volatile("s_waitcnt lgkmcnt(0)" ::: "memory"); \
                    __builtin_amdgcn_sched_barrier(0); } while (0)
#define VM(N) asm volatile("s_waitcnt vmcnt(" #N ")" ::: "memory")

// af[ii][kb] <- A row wm*64 + ii*16 + lr, k-chunk (kb*4+lk)^lr7
#define LDA(ABASE) do { \
  const char* _ba = (const char*)(ABASE); \
  _Pragma("unroll") for (int ii = 0; ii < 4; ++ii) { \
    int _row = wm*64 + ii*16 + lr; \
    _Pragma("unroll") for (int kb = 0; kb < 2; ++kb) \
      af[ii][kb] = *(const short8*)(_ba + _row*128 + (((kb*4+lk) ^ lr7) * 16)); \
  } \
} while (0)

#define LDB(BBASE) do { \
  const char* _bb = (const char*)(BBASE); \
  _Pragma("unroll") for (int jj = 0; jj < 4; ++jj) { \
    int _row = wn*64 + jj*16 + lr; \
    _Pragma("unroll") for (int kb = 0; kb < 2; ++kb) \
      bf[jj][kb] = *(const short8*)(_bb + _row*128 + (((kb*4+lk) ^ lr7) * 16)); \
  } \
} while (0)

#define MMA_ALL() do { \
  __builtin_amdgcn_s_setprio(1); \
  _Pragma("unroll") for (int ii = 0; ii < 4; ++ii) \
    _Pragma("unroll") for (int jj = 0; jj < 4; ++jj) \
      _Pragma("unroll") for (int kb = 0; kb < 2; ++kb) \
        acc[ii][jj] = __builtin_amdgcn_mfma_f32_16x16x32_bf16( \
            af[ii][kb], bf[jj][kb], acc[ii][jj], 0, 0, 0); \
  __builtin_amdgcn_s_setprio(0); \
} while (0)

// One K-tile: STG = stage T(kt+2) guard, VMN = vmcnt arg after staging
#define KTILE(AB, BB, KT, STG, VMARG) do { \
  LDA(AB); LDB(BB); LGK0(); \
  BAR(); \
  if (STG) { \
    stage_tile(Ag, mBase, K, (KT) + 2, AB, tid); \
    stage_tile(Bg, nBase, K, (KT) + 2, BB, tid); \
  } \
  MMA_ALL(); \
  VMARG; \
  BAR(); \
} while (0)

template<int OUT_BF16>
__global__ __launch_bounds__(256, 2)
void gemm128(const unsigned short* __restrict__ Ag,
             const unsigned short* __restrict__ Bg,
             const float* __restrict__ bias,
             void* __restrict__ Cout,
             int M, int N, int K, int tilesN) {
  __shared__ __align__(16) unsigned short lds[32768];   // 64 KiB

  int tid = threadIdx.x;
  int nwg = gridDim.x;                   // 1536 / 512, both %8==0
  int cpx = nwg >> 3;
  int wg  = ((int)blockIdx.x & 7) * cpx + ((int)blockIdx.x >> 3);  // XCD swizzle
  int tm = wg / tilesN, tn = wg % tilesN;
  long mBase = (long)tm * 128;
  long nBase = (long)tn * 128;

  int lane = tid & 63, wave = tid >> 6;
  int wm = wave >> 1;          // 0..1 : M half (64 rows)
  int wn = wave & 1;           // 0..1 : N half (64 cols)
  int lr = lane & 15, lk = lane >> 4, lr7 = lr & 7;

  unsigned short* A0 = lds;              // buf0 A (128x64)
  unsigned short* A1 = lds + 8192;       // buf1 A
  unsigned short* B0 = lds + 16384;      // buf0 B
  unsigned short* B1 = lds + 24576;      // buf1 B

  f32x4 acc[4][4];
  #pragma unroll
  for (int i = 0; i < 4; ++i)
    #pragma unroll
    for (int j = 0; j < 4; ++j) acc[i][j] = (f32x4){0.f, 0.f, 0.f, 0.f};

  short8 af[4][2], bf[4][2];

  // ---- prologue: T0 -> buf0, T1 -> buf1 (16 gll16/thread) ----
  stage_tile(Ag, mBase, K, 0, A0, tid);
  stage_tile(Bg, nBase, K, 0, B0, tid);
  stage_tile(Ag, mBase, K, 1, A1, tid);
  stage_tile(Bg, nBase, K, 1, B1, tid);
  VM(8);                       // T0 landed (T1's 8 in flight)
  BAR();

  // K = 512: tiles 0..7, unrolled in pairs (static buffer addressing)
  #pragma unroll 1
  for (int i = 0; i < 4; ++i) {
    int kt = 2 * i;
    if (i < 3) {
      KTILE(A0, B0, kt,     true,  VM(8));   // stages T(kt+2)
      KTILE(A1, B1, kt + 1, true,  VM(8));   // stages T(kt+3)
    } else {
      KTILE(A0, B0, kt,     false, VM(0));   // kt=6: drain T7
      KTILE(A1, B1, kt + 1, false, (void)0); // kt=7: nothing outstanding
    }
  }

  // ---- epilogue: C/D layout col = lane&15, row = (lane>>4)*4 + r --------
  long rowb = mBase + wm * 64 + (lane >> 4) * 4;
  int  colb = (int)nBase + wn * 64 + lr;
  if (OUT_BF16) {
    unsigned short* C = (unsigned short*)Cout;
    #pragma unroll
    for (int mi = 0; mi < 4; ++mi)
      #pragma unroll
      for (int nj = 0; nj < 4; ++nj) {
        int col = colb + nj * 16;
        float bv = bias[col];
        #pragma unroll
        for (int r = 0; r < 4; ++r)
          C[(rowb + mi * 16 + r) * (long)N + col] = f2b(acc[mi][nj][r] + bv);
      }
  } else {
    float* C = (float*)Cout;
    #pragma unroll
    for (int mi = 0; mi < 4; ++mi)
      #pragma unroll
      for (int nj = 0; nj < 4; ++nj) {
        int col = colb + nj * 16;
        float bv = bias[col];
        #pragma unroll
        for (int r = 0; r < 4; ++r)
          C[(rowb + mi * 16 + r) * (long)N + col] = acc[mi][nj][r] + bv;
      }
  }
}

// ---------------- neighborhood attention: 1 thread per (b,l,h) ------------
__global__ __launch_bounds__(256)
void natt(const unsigned short* __restrict__ qkv, const float* __restrict__ rpb,
          unsigned short* __restrict__ out) {
  int tid = blockIdx.x * 256 + threadIdx.x;
  int h = tid & 15;
  int l = (tid >> 4) & (NL - 1);
  int b = tid >> 16;
  const float scale = 0.17677669529663687f;

  long qb = ((long)(b * NL + l) * 3) * NC + h * HD;
  float q[HD];
  {
    const u16x8* q8 = (const u16x8*)(qkv + qb);
    #pragma unroll
    for (int w = 0; w < 4; ++w) {
      u16x8 u = q8[w];
      #pragma unroll
      for (int e = 0; e < 8; ++e) q[w * 8 + e] = b2f(u[e]) * scale;
    }
  }

  int ni = l - KHALF;
  if (ni < 0) ni = 0;
  if (ni > NL - KW) ni = NL - KW;
  const float* rb = rpb + h * (2 * KW - 1) + (ni - l + KW - 1);

  float p[KW];
  float mx = -1e30f;
  #pragma unroll
  for (int j = 0; j < KW; ++j) {
    long kb = ((long)(b * NL + ni + j) * 3 + 1) * NC + h * HD;
    const u16x8* k8 = (const u16x8*)(qkv + kb);
    float s = 0.f;
    #pragma unroll
    for (int w = 0; w < 4; ++w) {
      u16x8 u = k8[w];
      #pragma unroll
      for (int e = 0; e < 8; ++e) s += q[w * 8 + e] * b2f(u[e]);
    }
    s += rb[j];
    p[j] = s;
    mx = fmaxf(mx, s);
  }

  float sum = 0.f;
  #pragma unroll
  for (int j = 0; j < KW; ++j) { p[j] = __expf(p[j] - mx); sum += p[j]; }
  float inv = 1.0f / sum;

  float o[HD];
  #pragma unroll
  for (int d = 0; d < HD; ++d) o[d] = 0.f;
  #pragma unroll
  for (int j = 0; j < KW; ++j) {
    long vb = ((long)(b * NL + ni + j) * 3 + 2) * NC + h * HD;
    const u16x8* v8 = (const u16x8*)(qkv + vb);
    float wj = p[j] * inv;
    #pragma unroll
    for (int w = 0; w < 4; ++w) {
      u16x8 u = v8[w];
      #pragma unroll
      for (int e = 0; e < 8; ++e) o[w * 8 + e] += wj * b2f(u[e]);
    }
  }

  unsigned short* op = out + (long)(b * NL + l) * NC + h * HD;
  #pragma unroll
  for (int w = 0; w < 4; ++w) {
    u16x8 u;
    #pragma unroll
    for (int e = 0; e < 8; ++e) u[e] = f2b(o[w * 8 + e]);
    *((u16x8*)(op + w * 8)) = u;
  }
}

// ---------------------------------------------------------------------------
extern "C" void kernel_launch(void* const* d_in, const int* in_sizes, int n_in,
                              void* d_out, int out_size, void* d_ws, size_t ws_size,
                              hipStream_t stream) {
  const float* x      = (const float*)d_in[0];
  const float* qkv_w  = (const float*)d_in[1];
  const float* qkv_b  = (const float*)d_in[2];
  const float* rpb    = (const float*)d_in[3];
  const float* proj_w = (const float*)d_in[4];
  const float* proj_b = (const float*)d_in[5];
  float* out = (float*)d_out;

  char* ws = (char*)d_ws;
  unsigned short* xb     = (unsigned short*)(ws);              // 16,777,216 B
  unsigned short* qkvwT  = (unsigned short*)(ws + 16777216);   //  1,572,864 B
  unsigned short* projwT = (unsigned short*)(ws + 18350080);   //    524,288 B
  unsigned short* qkvo   = (unsigned short*)(ws + 18874368);   // 50,331,648 B
  unsigned short* attno  = (unsigned short*)(ws + 69206016);   // 16,777,216 B

  cvt_f32_bf16<<<dim3(4096), dim3(256), 0, stream>>>(x, xb);
  transpose_bf16<<<dim3(48, 16), dim3(32, 8), 0, stream>>>(qkv_w, qkvwT, 512, 1536);
  transpose_bf16<<<dim3(16, 16), dim3(32, 8), 0, stream>>>(proj_w, projwT, 512, 512);
  // qkv = x @ qkv_w + b   (bf16 out): 128 x 12 = 1536 blocks = 6/CU
  gemm128<1><<<dim3(1536), dim3(256), 0, stream>>>(xb, qkvwT, qkv_b, qkvo,
                                                   NM, 1536, 512, 12);
  natt<<<dim3(1024), dim3(256), 0, stream>>>(qkvo, rpb, attno);
  // out = attn @ proj_w + b  (fp32 out): 128 x 4 = 512 blocks = 2/CU
  gemm128<0><<<dim3(512), dim3(256), 0, stream>>>(attno, projwT, proj_b, out,
                                                  NM, 512, 512, 4);
}

// Round 8
// 97.414 us; speedup vs baseline: 1.1781x; 1.0429x over previous
//
#include <hip/hip_runtime.h>
#include <hip/hip_bf16.h>
#include <stdint.h>

// NeighborhoodAttention1D: B=4, L=4096, C=512, H=16, hd=32, K=13
// cvt(x)->bf16 ; pack W->frag-order bf16 ; GEMM (A-only LDS, B direct->regs) ;
// natt ; GEMM2 (same kernel)

typedef __attribute__((ext_vector_type(8))) short short8;   // 8 x bf16 frag
typedef __attribute__((ext_vector_type(4))) float f32x4;    // MFMA C/D frag
typedef __attribute__((ext_vector_type(8))) unsigned short u16x8;
typedef __attribute__((ext_vector_type(4))) float float4v;

#define NB 4
#define NL 4096
#define NC 512
#define NH 16
#define HD 32
#define KW 13
#define KHALF 6
#define NM (NB*NL)   // 16384 rows

__device__ __forceinline__ float b2f(unsigned short u) {
  union { unsigned int i; float f; } x; x.i = ((unsigned int)u) << 16; return x.f;
}
__device__ __forceinline__ unsigned short f2b(float f) {
  __hip_bfloat16 h = __float2bfloat16(f);   // RNE
  return __builtin_bit_cast(unsigned short, h);
}
__device__ __forceinline__ void gll16(const unsigned short* g, unsigned short* l) {
  __builtin_amdgcn_global_load_lds(
      (const __attribute__((address_space(1))) void*)g,
      (__attribute__((address_space(3))) void*)l, 16, 0, 0);
}

// ---------------- fp32 -> bf16 convert (x), 8 elems/thread ----------------
__global__ __launch_bounds__(256) void cvt_f32_bf16(const float* __restrict__ in,
                                                    unsigned short* __restrict__ out) {
  long i = (long)blockIdx.x * 256 + threadIdx.x;
  const float4v* in4 = (const float4v*)in;
  float4v a = in4[i * 2];
  float4v b = in4[i * 2 + 1];
  u16x8 u;
  u[0] = f2b(a.x); u[1] = f2b(a.y); u[2] = f2b(a.z); u[3] = f2b(a.w);
  u[4] = f2b(b.x); u[5] = f2b(b.y); u[6] = f2b(b.z); u[7] = f2b(b.w);
  ((u16x8*)out)[i] = u;
}

// ------ pack W[K][N] (fp32) -> Bf fragment-ordered bf16 --------------------
// Bf group g = (((tn*8 + kt)*2 + wn)*4 + nj)*2 + kb, lane, e(8):
//   n = tn*128 + wn*64 + nj*16 + (lane&15)
//   k = kt*64 + (kb*4 + (lane>>4))*8 + e
// In GEMM, wave (tn,wn) at K-tile kt loads frag (nj,kb) as ONE coalesced
// global_load_dwordx4 per lane: Bf[... + (nj*2+kb)*512 + lane*8].
__global__ __launch_bounds__(256)
void pack_bf(const float* __restrict__ W, unsigned short* __restrict__ Bf,
             int N, int ngroups) {
  int g = blockIdx.x * 256 + threadIdx.x;
  if (g >= ngroups) return;
  int lane = g & 63;
  int kb   = (g >> 6) & 1;
  int nj   = (g >> 7) & 3;
  int wn   = (g >> 9) & 1;
  int kt   = (g >> 10) & 7;
  int tn   = g >> 13;
  int n  = tn * 128 + wn * 64 + nj * 16 + (lane & 15);
  int k0 = kt * 64 + (kb * 4 + (lane >> 4)) * 8;
  u16x8 u;
  #pragma unroll
  for (int e = 0; e < 8; ++e) u[e] = f2b(W[(long)(k0 + e) * N + n]);
  ((u16x8*)Bf)[g] = u;
}

// ====== 128x128 bf16 GEMM: A-only LDS (32KB dbuf), B frag-direct to regs ===
// C[M,N] = A[M,K]*W + bias, W pre-packed. K=512 -> 8 K-tiles of 64.
// 256 threads = 4 waves (2M x 2N), per-wave 64x64 out = acc[4][4].
// R7 post-mortem: A+B-in-LDS moves 192KB LDS/CU/K-tile (>= 1500cyc) --
// the pipe every prior structure saturated. B here comes straight from
// L2 (1.5MB, resident) as 8 coalesced dwordx4/wave/K-tile -> LDS traffic
// halves and B-path decouples from barriers. LDS 32KB -> 3 blocks/CU.
// Per iter kt (A buf b=kt&1):
//   issue B(kt)->bf ; LDA(8 b128) ; lgkm0+schedbar ; BAR ;
//   gll A(kt+2)->buf b ; VM(4) ; MFMA ; BAR
// vmcnt ledger (issue order per iter: B(kt) x8, then gllA(kt+2) x4):
//   prologue: gllA(0)x4, gllA(1)x4, VM(4) -> A(0) landed, A(1) in flight.
//   iter kt (0..5): outstanding {A(kt+1)4, B(kt)8, A(kt+2)4}=16; VM(4)
//     waits 12 = A(kt+1)+B(kt) -> MFMA's B ready, next tile's A in LDS
//     (+ end-BAR syncs all waves' glls).  iter6: {A(7)4,B(6)8} VM(0).
//   iter7: {B(7)8} VM(0).  WAR: gll into buf b after BAR ending its reads.
// Swizzle (A only): chunk ^= (row&7), both-sides (verified 0 conflicts).

__device__ __forceinline__ void stage_tileA(const unsigned short* __restrict__ G,
                                            long rowBase, int K, int kt,
                                            unsigned short* ldsDst, int tid) {
  int r  = tid >> 3;                       // 0..31
  int ch = (tid & 7) ^ (r & 7);            // inverse-swizzled source chunk
  const unsigned short* s0 = G + (rowBase + r) * (long)K + kt * 64 + ch * 8;
  unsigned short* d0 = ldsDst + tid * 8;
  #pragma unroll
  for (int q = 0; q < 4; ++q)              // rows r, r+32, r+64, r+96
    gll16(s0 + (long)32 * q * K, d0 + 2048 * q);
}

#define BAR() __builtin_amdgcn_s_barrier()
#define LGK0() do { asm volatile("s_waitcnt lgkmcnt(0)" ::: "memory"); \
                    __builtin_amdgcn_sched_barrier(0); } while (0)
#define VM(N) asm volatile("s_waitcnt vmcnt(" #N ")" ::: "memory")

// af[ii][kb] <- A row wm*64 + ii*16 + lr, k-chunk (kb*4+lk)^lr7 (swizzled)
#define LDA(ABASE) do { \
  const char* _ba = (const char*)(ABASE); \
  _Pragma("unroll") for (int ii = 0; ii < 4; ++ii) { \
    int _row = wm*64 + ii*16 + lr; \
    _Pragma("unroll") for (int kb = 0; kb < 2; ++kb) \
      af[ii][kb] = *(const short8*)(_ba + _row*128 + (((kb*4+lk) ^ lr7) * 16)); \
  } \
} while (0)

// bf[nj][kb] <- packed B frags for K-tile KT (8 coalesced 16B loads)
#define LDBG(KT) do { \
  const short8* _bp = (const short8*)(Bfw + (long)(KT) * 8192) + lane; \
  _Pragma("unroll") for (int nj = 0; nj < 4; ++nj) \
    _Pragma("unroll") for (int kb = 0; kb < 2; ++kb) \
      bf[nj][kb] = _bp[(nj*2 + kb) * 64]; \
} while (0)

#define MMA_ALL() do { \
  __builtin_amdgcn_s_setprio(1); \
  _Pragma("unroll") for (int ii = 0; ii < 4; ++ii) \
    _Pragma("unroll") for (int jj = 0; jj < 4; ++jj) \
      _Pragma("unroll") for (int kb = 0; kb < 2; ++kb) \
        acc[ii][jj] = __builtin_amdgcn_mfma_f32_16x16x32_bf16( \
            af[ii][kb], bf[jj][kb], acc[ii][jj], 0, 0, 0); \
  __builtin_amdgcn_s_setprio(0); \
} while (0)

#define GTILE(ABUF, KT, STG, VMARG) do { \
  LDBG(KT); \
  LDA(ABUF); \
  LGK0(); \
  BAR(); \
  if (STG) stage_tileA(Ag, mBase, K, (KT) + 2, ABUF, tid); \
  VMARG; \
  MMA_ALL(); \
  BAR(); \
} while (0)

template<int OUT_BF16>
__global__ __launch_bounds__(256, 3)
void gemm128(const unsigned short* __restrict__ Ag,
             const unsigned short* __restrict__ Bf,
             const float* __restrict__ bias,
             void* __restrict__ Cout,
             int M, int N, int K, int tilesN) {
  __shared__ __align__(16) unsigned short lds[16384];   // 32 KiB (A dbuf)

  int tid = threadIdx.x;
  int nwg = gridDim.x;                   // 1536 / 512, both %8==0
  int cpx = nwg >> 3;
  int wg  = ((int)blockIdx.x & 7) * cpx + ((int)blockIdx.x >> 3);  // XCD swizzle
  int tm = wg / tilesN, tn = wg % tilesN;
  long mBase = (long)tm * 128;
  long nBase = (long)tn * 128;

  int lane = tid & 63, wave = tid >> 6;
  int wm = wave >> 1;          // 0..1 : M half (64 rows)
  int wn = wave & 1;           // 0..1 : N half (64 cols)
  int lr = lane & 15, lk = lane >> 4, lr7 = lr & 7;

  const unsigned short* Bfw = Bf + (long)tn * 65536 + wn * 4096;

  unsigned short* A0 = lds;              // buf0 A (128x64)
  unsigned short* A1 = lds + 8192;       // buf1 A

  f32x4 acc[4][4];
  #pragma unroll
  for (int i = 0; i < 4; ++i)
    #pragma unroll
    for (int j = 0; j < 4; ++j) acc[i][j] = (f32x4){0.f, 0.f, 0.f, 0.f};

  short8 af[4][2], bf[4][2];

  // ---- prologue: A(0)->buf0, A(1)->buf1 (8 gll16/thread) ----
  stage_tileA(Ag, mBase, K, 0, A0, tid);
  stage_tileA(Ag, mBase, K, 1, A1, tid);
  VM(4);                       // A(0) landed (A(1)'s 4 in flight)
  BAR();

  #pragma unroll 1
  for (int i = 0; i < 3; ++i) {
    GTILE(A0, 2*i,     true, VM(4));
    GTILE(A1, 2*i + 1, true, VM(4));
  }
  GTILE(A0, 6, false, VM(0));
  GTILE(A1, 7, false, VM(0));

  // ---- epilogue: C/D layout col = lane&15, row = (lane>>4)*4 + r --------
  long rowb = mBase + wm * 64 + (lane >> 4) * 4;
  int  colb = (int)nBase + wn * 64 + lr;
  if (OUT_BF16) {
    unsigned short* C = (unsigned short*)Cout;
    #pragma unroll
    for (int mi = 0; mi < 4; ++mi)
      #pragma unroll
      for (int nj = 0; nj < 4; ++nj) {
        int col = colb + nj * 16;
        float bv = bias[col];
        #pragma unroll
        for (int r = 0; r < 4; ++r)
          C[(rowb + mi * 16 + r) * (long)N + col] = f2b(acc[mi][nj][r] + bv);
      }
  } else {
    float* C = (float*)Cout;
    #pragma unroll
    for (int mi = 0; mi < 4; ++mi)
      #pragma unroll
      for (int nj = 0; nj < 4; ++nj) {
        int col = colb + nj * 16;
        float bv = bias[col];
        #pragma unroll
        for (int r = 0; r < 4; ++r)
          C[(rowb + mi * 16 + r) * (long)N + col] = acc[mi][nj][r] + bv;
      }
  }
}

// ---------------- neighborhood attention: 1 thread per (b,l,h) ------------
__global__ __launch_bounds__(256)
void natt(const unsigned short* __restrict__ qkv, const float* __restrict__ rpb,
          unsigned short* __restrict__ out) {
  int tid = blockIdx.x * 256 + threadIdx.x;
  int h = tid & 15;
  int l = (tid >> 4) & (NL - 1);
  int b = tid >> 16;
  const float scale = 0.17677669529663687f;

  long qb = ((long)(b * NL + l) * 3) * NC + h * HD;
  float q[HD];
  {
    const u16x8* q8 = (const u16x8*)(qkv + qb);
    #pragma unroll
    for (int w = 0; w < 4; ++w) {
      u16x8 u = q8[w];
      #pragma unroll
      for (int e = 0; e < 8; ++e) q[w * 8 + e] = b2f(u[e]) * scale;
    }
  }

  int ni = l - KHALF;
  if (ni < 0) ni = 0;
  if (ni > NL - KW) ni = NL - KW;
  const float* rb = rpb + h * (2 * KW - 1) + (ni - l + KW - 1);

  float p[KW];
  float mx = -1e30f;
  #pragma unroll
  for (int j = 0; j < KW; ++j) {
    long kb = ((long)(b * NL + ni + j) * 3 + 1) * NC + h * HD;
    const u16x8* k8 = (const u16x8*)(qkv + kb);
    float s = 0.f;
    #pragma unroll
    for (int w = 0; w < 4; ++w) {
      u16x8 u = k8[w];
      #pragma unroll
      for (int e = 0; e < 8; ++e) s += q[w * 8 + e] * b2f(u[e]);
    }
    s += rb[j];
    p[j] = s;
    mx = fmaxf(mx, s);
  }

  float sum = 0.f;
  #pragma unroll
  for (int j = 0; j < KW; ++j) { p[j] = __expf(p[j] - mx); sum += p[j]; }
  float inv = 1.0f / sum;

  float o[HD];
  #pragma unroll
  for (int d = 0; d < HD; ++d) o[d] = 0.f;
  #pragma unroll
  for (int j = 0; j < KW; ++j) {
    long vb = ((long)(b * NL + ni + j) * 3 + 2) * NC + h * HD;
    const u16x8* v8 = (const u16x8*)(qkv + vb);
    float wj = p[j] * inv;
    #pragma unroll
    for (int w = 0; w < 4; ++w) {
      u16x8 u = v8[w];
      #pragma unroll
      for (int e = 0; e < 8; ++e) o[w * 8 + e] += wj * b2f(u[e]);
    }
  }

  unsigned short* op = out + (long)(b * NL + l) * NC + h * HD;
  #pragma unroll
  for (int w = 0; w < 4; ++w) {
    u16x8 u;
    #pragma unroll
    for (int e = 0; e < 8; ++e) u[e] = f2b(o[w * 8 + e]);
    *((u16x8*)(op + w * 8)) = u;
  }
}

// ---------------------------------------------------------------------------
extern "C" void kernel_launch(void* const* d_in, const int* in_sizes, int n_in,
                              void* d_out, int out_size, void* d_ws, size_t ws_size,
                              hipStream_t stream) {
  const float* x      = (const float*)d_in[0];
  const float* qkv_w  = (const float*)d_in[1];
  const float* qkv_b  = (const float*)d_in[2];
  const float* rpb    = (const float*)d_in[3];
  const float* proj_w = (const float*)d_in[4];
  const float* proj_b = (const float*)d_in[5];
  float* out = (float*)d_out;

  char* ws = (char*)d_ws;
  unsigned short* xb   = (unsigned short*)(ws);              // 16,777,216 B
  unsigned short* Bf1  = (unsigned short*)(ws + 16777216);   //  1,572,864 B
  unsigned short* Bf2  = (unsigned short*)(ws + 18350080);   //    524,288 B
  unsigned short* qkvo = (unsigned short*)(ws + 18874368);   // 50,331,648 B
  unsigned short* attno= (unsigned short*)(ws + 69206016);   // 16,777,216 B

  cvt_f32_bf16<<<dim3(4096), dim3(256), 0, stream>>>(x, xb);
  // pack weights into MFMA-fragment order (replaces transposes)
  pack_bf<<<dim3(384), dim3(256), 0, stream>>>(qkv_w, Bf1, 1536, 98304);
  pack_bf<<<dim3(128), dim3(256), 0, stream>>>(proj_w, Bf2, 512, 32768);
  // qkv = x @ qkv_w + b   (bf16 out): 128 x 12 = 1536 blocks
  gemm128<1><<<dim3(1536), dim3(256), 0, stream>>>(xb, Bf1, qkv_b, qkvo,
                                                   NM, 1536, 512, 12);
  natt<<<dim3(1024), dim3(256), 0, stream>>>(qkvo, rpb, attno);
  // out = attn @ proj_w + b  (fp32 out): 128 x 4 = 512 blocks
  gemm128<0><<<dim3(512), dim3(256), 0, stream>>>(attno, Bf2, proj_b, out,
                                                  NM, 512, 512, 4);
}